// Round 7
// baseline (357.975 us; speedup 1.0000x reference)
//
#include <hip/hip_runtime.h>
#include <cstddef>

#define PB 4096  // points per batch
static constexpr float SCALE_F = 0.17677669529663687f;  // 32^-0.5

typedef __attribute__((ext_vector_type(8))) short bf16x8;
typedef __attribute__((ext_vector_type(4))) float f32x4;

static __device__ __forceinline__ unsigned short f2bf(float x) {
  unsigned u = __builtin_bit_cast(unsigned, x);
  u += 0x7fffu + ((u >> 16) & 1u);  // RNE
  return (unsigned short)(u >> 16);
}
static __device__ __forceinline__ float bf2f(unsigned short h) {
  return __builtin_bit_cast(float, (unsigned)h << 16);
}

// ---------------------------------------------------------------------------
// kNN: one wave per query; sorted top-32 distributed over lanes 0..31.
// fp32 distances with explicit rounding = exactly the reference's arithmetic.
// ---------------------------------------------------------------------------
__global__ __launch_bounds__(64) void knn_kernel(const float* __restrict__ xyz,
                                                 int* __restrict__ idx_out) {
  const int g = blockIdx.x;          // 0 .. B*PB-1
  const int b = g >> 12;
  const int p = g & (PB - 1);
  const int lane = threadIdx.x;
  const float* base = xyz + (size_t)b * PB * 3;
  const float qx = base[p * 3 + 0];
  const float qy = base[p * 3 + 1];
  const float qz = base[p * 3 + 2];
  float list_d = 3.4e38f;  // lanes 0..31 hold the sorted list
  int list_i = -1;
  for (int c = 0; c < PB / 64; ++c) {
    const int j = (c << 6) + lane;
    const float dx = __fsub_rn(qx, base[j * 3 + 0]);
    const float dy = __fsub_rn(qy, base[j * 3 + 1]);
    const float dz = __fsub_rn(qz, base[j * 3 + 2]);
    const float d2 = __fadd_rn(__fadd_rn(__fmul_rn(dx, dx), __fmul_rn(dy, dy)),
                               __fmul_rn(dz, dz));
    float worst = __shfl(list_d, 31);
    unsigned long long mask = __ballot(d2 < worst);
    while (mask) {
      const int l = __ffsll(mask) - 1;
      mask &= mask - 1;
      const float v = __shfl(d2, l);
      worst = __shfl(list_d, 31);
      if (v < worst) {
        const unsigned long long gt = __ballot((lane < 32) && (list_d > v));
        const int pos = __ffsll(gt) - 1;
        const float pd = __shfl_up(list_d, 1);
        const int pi = __shfl_up(list_i, 1);
        if (lane < 32 && lane >= pos) {
          const bool at = (lane == pos);
          list_d = at ? v : pd;
          list_i = at ? ((c << 6) + l) : pi;
        }
      }
    }
  }
  if (lane < 32) idx_out[(size_t)g * 32 + lane] = list_i;
}

// ---------------------------------------------------------------------------
// Weight prep: bf16 hi/lo of Wq,Wk,Wv,Wp + single-bf16 W2.
// ---------------------------------------------------------------------------
__global__ __launch_bounds__(256) void prep_w(
    const float* __restrict__ Wq, const float* __restrict__ Wk,
    const float* __restrict__ Wv, const float* __restrict__ Wp,
    const float* __restrict__ W2,
    unsigned short* __restrict__ whi, unsigned short* __restrict__ wlo,
    unsigned short* __restrict__ w2bf) {
  const int blk = blockIdx.x;
  const int tid = threadIdx.x;
  if (blk < 1024) {
    const int e = blk * 256 + tid;     // 0 .. 262143
    const int m = e >> 16;
    const int off = e & 65535;
    const float* src = (m == 0) ? Wq : (m == 1) ? Wk : (m == 2) ? Wv : Wp;
    const float x = src[off];
    const unsigned short hi = f2bf(x);
    whi[e] = hi;
    wlo[e] = f2bf(x - bf2f(hi));
  } else {
    const int off = (blk - 1024) * 256 + tid;  // 0 .. 65535
    w2bf[off] = f2bf(W2[off]);
  }
}

// Wqu[(h,m)][i] = sum_{t<32} Wq[h*32+t][i] * W2[h*32+t][m]   (bf16 out)
__global__ __launch_bounds__(256) void wqu_kernel(
    const float* __restrict__ Wq, const float* __restrict__ W2,
    unsigned short* __restrict__ wqu_t) {
  __shared__ float w2s[32];
  const int hm = blockIdx.x;          // 0..2047
  const int h = hm >> 8;
  const int m = hm & 255;
  const int tid = threadIdx.x;        // = i
  if (tid < 32) w2s[tid] = W2[(size_t)((h << 5) + tid) * 256 + m];
  __syncthreads();
  float a = 0.f;
#pragma unroll 8
  for (int t = 0; t < 32; ++t)
    a += Wq[(size_t)((h << 5) + t) * 256 + tid] * w2s[t];
  wqu_t[(size_t)hm * 256 + tid] = f2bf(a);
}

// Wop_t[j][(h,m)] = sum_{t<32} W2[h*32+t][m] * Wp[j][h*32+t]   (bf16 out)
__global__ __launch_bounds__(256) void wop_kernel(
    const float* __restrict__ W2, const float* __restrict__ Wp,
    unsigned short* __restrict__ wop_t) {
  __shared__ float wps[32];
  const int blk = blockIdx.x;         // 0..2047
  const int j = blk & 255;
  const int h = blk >> 8;
  const int tid = threadIdx.x;        // = m
  if (tid < 32) wps[tid] = Wp[(size_t)j * 256 + (h << 5) + tid];
  __syncthreads();
  float a = 0.f;
#pragma unroll 8
  for (int t = 0; t < 32; ++t)
    a += W2[(size_t)((h << 5) + t) * 256 + tid] * wps[t];
  wop_t[(size_t)j * 2048 + (h << 8) + tid] = f2bf(a);
}

// bpp[j] = bp[j] + sum_n b2[n] * Wp[j][n]
__global__ __launch_bounds__(256) void bpp_kernel(
    const float* __restrict__ b2, const float* __restrict__ Wp,
    const float* __restrict__ bp, float* __restrict__ bpp) {
  __shared__ float b2s[256];
  const int tid = threadIdx.x;
  b2s[tid] = b2[tid];
  __syncthreads();
  float a = bp[tid];
  for (int n = 0; n < 256; ++n) a += b2s[n] * Wp[(size_t)tid * 256 + n];
  bpp[tid] = a;
}

// ---------------------------------------------------------------------------
// bf16x3 MFMA GEMM core: acc = A[r0..r0+31][:] @ W^T (W row-major hi/lo bf16).
// ---------------------------------------------------------------------------
static __device__ __forceinline__ void gemm32_core(
    const float* __restrict__ A, const unsigned short* __restrict__ wh,
    const unsigned short* __restrict__ wl, const int r0,
    unsigned short* ah, unsigned short* al, f32x4 acc[2][4]) {
  const int tid = threadIdx.x;
#pragma unroll
  for (int t = 0; t < 8; ++t) {
    const int idx4 = (t << 8) + tid;     // 2048 float4-slots = 32 rows x 64
    const int row = idx4 >> 6;
    const int c4 = idx4 & 63;
    const float4 v = *(const float4*)(A + (size_t)(r0 + row) * 256 + (c4 << 2));
    const unsigned short h0 = f2bf(v.x), h1 = f2bf(v.y);
    const unsigned short h2 = f2bf(v.z), h3 = f2bf(v.w);
    const unsigned short l0 = f2bf(v.x - bf2f(h0)), l1 = f2bf(v.y - bf2f(h1));
    const unsigned short l2 = f2bf(v.z - bf2f(h2)), l3 = f2bf(v.w - bf2f(h3));
    const int base = (row << 9) + ((c4 << 3) ^ ((row & 7) << 4));
    *(uint2*)((char*)ah + base) =
        make_uint2((unsigned)h0 | ((unsigned)h1 << 16),
                   (unsigned)h2 | ((unsigned)h3 << 16));
    *(uint2*)((char*)al + base) =
        make_uint2((unsigned)l0 | ((unsigned)l1 << 16),
                   (unsigned)l2 | ((unsigned)l3 << 16));
  }
  __syncthreads();
  const int lane = tid & 63;
  const int w = tid >> 6;
  const int il = lane & 15;
  const int q4 = lane >> 4;
#pragma unroll
  for (int mt = 0; mt < 2; ++mt)
#pragma unroll
    for (int nt = 0; nt < 4; ++nt) acc[mt][nt] = (f32x4){0.f, 0.f, 0.f, 0.f};
#pragma unroll 2
  for (int ks = 0; ks < 8; ++ks) {
    bf16x8 bh[4], bl[4], a0[2], a1[2];
#pragma unroll
    for (int nt = 0; nt < 4; ++nt) {
      const int n = (w << 6) + (nt << 4) + il;
      const size_t off = (size_t)n * 256 + (ks << 5) + (q4 << 3);
      bh[nt] = *(const bf16x8*)(wh + off);
      bl[nt] = *(const bf16x8*)(wl + off);
    }
#pragma unroll
    for (int mt = 0; mt < 2; ++mt) {
      const int row = (mt << 4) + il;
      const int byte = (row << 9) + ((((ks << 5) + (q4 << 3)) << 1) ^ ((row & 7) << 4));
      a0[mt] = *(const bf16x8*)((const char*)ah + byte);
      a1[mt] = *(const bf16x8*)((const char*)al + byte);
    }
#pragma unroll
    for (int mt = 0; mt < 2; ++mt)
#pragma unroll
      for (int nt = 0; nt < 4; ++nt) {
        acc[mt][nt] = __builtin_amdgcn_mfma_f32_16x16x32_bf16(a0[mt], bh[nt], acc[mt][nt], 0, 0, 0);
        acc[mt][nt] = __builtin_amdgcn_mfma_f32_16x16x32_bf16(a1[mt], bh[nt], acc[mt][nt], 0, 0, 0);
        acc[mt][nt] = __builtin_amdgcn_mfma_f32_16x16x32_bf16(a0[mt], bl[nt], acc[mt][nt], 0, 0, 0);
      }
  }
}

// q -> fp32; k,v -> bf16
__global__ __launch_bounds__(256) void qkv_mfma(
    const float* __restrict__ feats,
    const unsigned short* __restrict__ whi, const unsigned short* __restrict__ wlo,
    float* __restrict__ qb, unsigned short* __restrict__ kb16,
    unsigned short* __restrict__ vb16) {
  __shared__ __align__(16) unsigned short ah[32 * 256];
  __shared__ __align__(16) unsigned short al[32 * 256];
  const int bid = blockIdx.x;
  const int sel = bid % 3;
  const int r0 = (bid / 3) << 5;
  const unsigned short* wh = whi + (size_t)sel * 65536;
  const unsigned short* wl = wlo + (size_t)sel * 65536;
  f32x4 acc[2][4];
  gemm32_core(feats, wh, wl, r0, ah, al, acc);
  const int tid = threadIdx.x;
  const int lane = tid & 63;
  const int w = tid >> 6;
  const int il = lane & 15;
  const int q4 = lane >> 4;
#pragma unroll
  for (int mt = 0; mt < 2; ++mt)
#pragma unroll
    for (int nt = 0; nt < 4; ++nt) {
      const int col = (w << 6) + (nt << 4) + il;
#pragma unroll
      for (int r = 0; r < 4; ++r) {
        const size_t e = (size_t)(r0 + (mt << 4) + (q4 << 2) + r) * 256 + col;
        if (sel == 0) qb[e] = acc[mt][nt][r];
        else if (sel == 1) kb16[e] = f2bf(acc[mt][nt][r]);
        else vb16[e] = f2bf(acc[mt][nt][r]);
      }
    }
}

// U[8192][2048] = feats @ Wqu^T, single-bf16
__global__ __launch_bounds__(256) void u_mfma(
    const float* __restrict__ feats, const unsigned short* __restrict__ wqu_t,
    unsigned short* __restrict__ U) {
  __shared__ __align__(16) unsigned short ah[32 * 256];
  const int r0 = blockIdx.x << 5;
  const int cb = blockIdx.y;          // 0..7 column block of 256
  const int tid = threadIdx.x;
#pragma unroll
  for (int t = 0; t < 8; ++t) {
    const int idx4 = (t << 8) + tid;
    const int row = idx4 >> 6;
    const int c4 = idx4 & 63;
    const float4 v = *(const float4*)(feats + (size_t)(r0 + row) * 256 + (c4 << 2));
    const int base = (row << 9) + ((c4 << 3) ^ ((row & 7) << 4));
    *(uint2*)((char*)ah + base) =
        make_uint2((unsigned)f2bf(v.x) | ((unsigned)f2bf(v.y) << 16),
                   (unsigned)f2bf(v.z) | ((unsigned)f2bf(v.w) << 16));
  }
  __syncthreads();
  const unsigned short* wh = wqu_t + (size_t)cb * 65536;
  const int lane = tid & 63;
  const int w = tid >> 6;
  const int il = lane & 15;
  const int q4 = lane >> 4;
  f32x4 acc[2][4];
#pragma unroll
  for (int mt = 0; mt < 2; ++mt)
#pragma unroll
    for (int nt = 0; nt < 4; ++nt) acc[mt][nt] = (f32x4){0.f, 0.f, 0.f, 0.f};
#pragma unroll 2
  for (int ks = 0; ks < 8; ++ks) {
    bf16x8 bh[4], a0[2];
#pragma unroll
    for (int nt = 0; nt < 4; ++nt) {
      const int n = (w << 6) + (nt << 4) + il;
      bh[nt] = *(const bf16x8*)(wh + (size_t)n * 256 + (ks << 5) + (q4 << 3));
    }
#pragma unroll
    for (int mt = 0; mt < 2; ++mt) {
      const int row = (mt << 4) + il;
      const int byte = (row << 9) + ((((ks << 5) + (q4 << 3)) << 1) ^ ((row & 7) << 4));
      a0[mt] = *(const bf16x8*)((const char*)ah + byte);
    }
#pragma unroll
    for (int mt = 0; mt < 2; ++mt)
#pragma unroll
      for (int nt = 0; nt < 4; ++nt)
        acc[mt][nt] = __builtin_amdgcn_mfma_f32_16x16x32_bf16(a0[mt], bh[nt], acc[mt][nt], 0, 0, 0);
  }
#pragma unroll
  for (int mt = 0; mt < 2; ++mt)
#pragma unroll
    for (int nt = 0; nt < 4; ++nt) {
      const int col = (w << 6) + (nt << 4) + il;
#pragma unroll
      for (int r = 0; r < 4; ++r)
        U[(size_t)(r0 + (mt << 4) + (q4 << 2) + r) * 2048 + (cb << 8) + col] =
            f2bf(acc[mt][nt][r]);
    }
}

// proj: out = A @ Wp^T (+ c16 @ Wop^T if FOLD) + bias
template <bool FOLD>
__global__ __launch_bounds__(256) void proj_mfma(
    const float* __restrict__ A,
    const unsigned short* __restrict__ whi, const unsigned short* __restrict__ wlo,
    const unsigned short* __restrict__ c16, const unsigned short* __restrict__ wop_t,
    const float* __restrict__ bias, float* __restrict__ C) {
  __shared__ __align__(16) unsigned short ah[32 * 256];
  __shared__ __align__(16) unsigned short al[32 * 256];
  const int r0 = blockIdx.x << 5;
  f32x4 acc[2][4];
  gemm32_core(A, whi, wlo, r0, ah, al, acc);
  const int tid = threadIdx.x;
  const int lane = tid & 63;
  const int w = tid >> 6;
  const int il = lane & 15;
  const int q4 = lane >> 4;
  if (FOLD) {
#pragma unroll 4
    for (int ks2 = 0; ks2 < 64; ++ks2) {
      bf16x8 af[2];
#pragma unroll
      for (int mt = 0; mt < 2; ++mt)
        af[mt] = *(const bf16x8*)(c16 + (size_t)(r0 + (mt << 4) + il) * 2048 +
                                  (ks2 << 5) + (q4 << 3));
#pragma unroll
      for (int nt = 0; nt < 4; ++nt) {
        const int n = (w << 6) + (nt << 4) + il;
        const bf16x8 bf = *(const bf16x8*)(wop_t + (size_t)n * 2048 +
                                           (ks2 << 5) + (q4 << 3));
#pragma unroll
        for (int mt = 0; mt < 2; ++mt)
          acc[mt][nt] = __builtin_amdgcn_mfma_f32_16x16x32_bf16(af[mt], bf, acc[mt][nt], 0, 0, 0);
      }
    }
  }
#pragma unroll
  for (int mt = 0; mt < 2; ++mt)
#pragma unroll
    for (int nt = 0; nt < 4; ++nt) {
      const int col = (w << 6) + (nt << 4) + il;
      const float bv = bias[col];
#pragma unroll
      for (int r = 0; r < 4; ++r)
        C[(size_t)(r0 + (mt << 4) + (q4 << 2) + r) * 256 + col] = acc[mt][nt][r] + bv;
    }
}

// ---------------------------------------------------------------------------
// fused_big: algebraic form, MFMA'd inner products, u from precomputed ubuf.
// 80-byte pitch on [m][k] tiles keeps all ds_read_b128 16B-aligned.
// ---------------------------------------------------------------------------
__global__ __launch_bounds__(256) void fused_big(
    const float* __restrict__ xyz, const int* __restrict__ nbr_idx,
    const float* __restrict__ qbuf, const unsigned short* __restrict__ kb16,
    const unsigned short* __restrict__ vb16,
    const float* __restrict__ W1, const float* __restrict__ b1,
    const unsigned short* __restrict__ ubuf,
    unsigned short* __restrict__ c16, float* __restrict__ o_pre) {
  __shared__ __align__(16) unsigned short h_km[32 * 256];  // 16KB swizzled
  __shared__ __align__(16) char h_mk[256 * 80];            // 20KB, pitch 80
  __shared__ __align__(16) unsigned short u16l[16 * 256];  // 8KB swizzled, rows 8+ zero
  __shared__ float sc_part[4][32][9];
  __shared__ float at_lds[32][9];
  __shared__ __align__(16) char at16[16 * 80];             // pitch 80, rows 8+ zero
  __shared__ float q_lds[256];
  __shared__ float rel[32][3];
  __shared__ int nbr_s[32];

  const int g = blockIdx.x;
  const int b = g >> 12;
  const int p = g & (PB - 1);
  const int tid = threadIdx.x;

  // ---- phase 0: stage + zero-init
  if (tid < 32) {
    const int j = nbr_idx[(size_t)g * 32 + tid];
    nbr_s[tid] = j;
    const float* xb = xyz + (size_t)b * PB * 3;
    rel[tid][0] = xb[j * 3 + 0] - xb[p * 3 + 0];
    rel[tid][1] = xb[j * 3 + 1] - xb[p * 3 + 1];
    rel[tid][2] = xb[j * 3 + 2] - xb[p * 3 + 2];
  }
  q_lds[tid] = qbuf[(size_t)g * 256 + tid];
  *(uint4*)((char*)u16l + 4096 + tid * 16) = make_uint4(0, 0, 0, 0);
  if (tid < 160) *(unsigned*)(at16 + 640 + tid * 4) = 0;
  __syncthreads();

  // ---- phase 1: H = relu(relpos @ W1^T + b1), both layouts
  {
    const int half = tid >> 7;
    const int c0 = (tid & 127) << 1;
    const int stg = (tid >> 1) & 7;
    const float w00 = W1[c0 * 3 + 0], w01 = W1[c0 * 3 + 1], w02 = W1[c0 * 3 + 2];
    const float w10 = W1[c0 * 3 + 3], w11 = W1[c0 * 3 + 4], w12 = W1[c0 * 3 + 5];
    const float bb0 = b1[c0], bb1 = b1[c0 + 1];
#pragma unroll 4
    for (int rl = 0; rl < 16; ++rl) {
      const int rr = (half << 4) | ((rl + stg) & 15);
      const float rx = rel[rr][0], ry = rel[rr][1], rz = rel[rr][2];
      const float h0 = fmaxf(bb0 + rx * w00 + ry * w01 + rz * w02, 0.f);
      const float h1 = fmaxf(bb1 + rx * w10 + ry * w11 + rz * w12, 0.f);
      const unsigned short bh0 = f2bf(h0), bh1 = f2bf(h1);
      *(unsigned*)((char*)h_km + (rr << 9) + (((unsigned)c0 << 1) ^ ((rr & 7) << 4))) =
          (unsigned)bh0 | ((unsigned)bh1 << 16);
      *(unsigned short*)(h_mk + c0 * 80 + rr * 2) = bh0;
      *(unsigned short*)(h_mk + (c0 + 1) * 80 + rr * 2) = bh1;
    }
  }
  // ---- phase 1b: u16l rows 0..7 from ubuf (swizzled like h_km)
  {
    const int h = tid >> 5;
    const int byte = (h << 9) + ((((tid & 31) << 4)) ^ ((h & 7) << 4));
    const uint4 uv = *(const uint4*)(ubuf + (size_t)g * 2048 + tid * 8);
    *(uint4*)((char*)u16l + byte) = uv;
  }
  __syncthreads();

  const int lane = tid & 63;
  const int w = tid >> 6;
  const int il = lane & 15;
  const int q4 = lane >> 4;
  const int kk = tid & 31;
  const int hh = tid >> 5;

  // ---- phase 2: s_qk (scalar) + S_pos (MFMA partials over m-chunks)
  float sqk = 0.f;
  {
    const int j = nbr_s[kk];
    const unsigned short* krow = kb16 + ((size_t)(b << 12) + j) * 256 + (hh << 5);
#pragma unroll
    for (int c4 = 0; c4 < 4; ++c4) {
      const bf16x8 kv = *(const bf16x8*)(krow + (c4 << 3));
#pragma unroll
      for (int jj = 0; jj < 8; ++jj)
        sqk += q_lds[(hh << 5) + (c4 << 3) + jj] * bf2f((unsigned short)kv[jj]);
    }
  }
  {
    f32x4 accp[2];
    accp[0] = (f32x4){0.f, 0.f, 0.f, 0.f};
    accp[1] = (f32x4){0.f, 0.f, 0.f, 0.f};
#pragma unroll
    for (int ksl = 0; ksl < 2; ++ksl) {
      const int m0 = (w << 6) + (ksl << 5) + (q4 << 3);  // element index
      const bf16x8 bfr = *(const bf16x8*)((char*)u16l + (il << 9) +
                                          (((unsigned)m0 << 1) ^ ((il & 7) << 4)));
#pragma unroll
      for (int mt = 0; mt < 2; ++mt) {
        const int row = (mt << 4) + il;
        const bf16x8 afr = *(const bf16x8*)((char*)h_km + (row << 9) +
                                            (((unsigned)m0 << 1) ^ ((row & 7) << 4)));
        accp[mt] = __builtin_amdgcn_mfma_f32_16x16x32_bf16(afr, bfr, accp[mt], 0, 0, 0);
      }
    }
    if (il < 8) {
#pragma unroll
      for (int mt = 0; mt < 2; ++mt)
#pragma unroll
        for (int r = 0; r < 4; ++r)
          sc_part[w][(mt << 4) + (q4 << 2) + r][il] = accp[mt][r];
    }
  }
  __syncthreads();

  // ---- phase 2b: combine + softmax + attn writes
  {
    float s = sqk + sc_part[0][kk][hh] + sc_part[1][kk][hh] +
              sc_part[2][kk][hh] + sc_part[3][kk][hh];
    s *= SCALE_F;
    float mx = s;
#pragma unroll
    for (int off = 16; off; off >>= 1) mx = fmaxf(mx, __shfl_xor(mx, off));
    const float e = __expf(s - mx);
    float ssum = e;
#pragma unroll
    for (int off = 16; off; off >>= 1) ssum += __shfl_xor(ssum, off);
    const float a = e / ssum;
    at_lds[kk][hh] = a;
    *(unsigned short*)(at16 + hh * 80 + kk * 2) = f2bf(a);
  }
  __syncthreads();

  // ---- phase 3: C8 = attn16 @ H -> c16 global (overwrites ubuf row g)
  {
    const bf16x8 afr = *(const bf16x8*)(at16 + il * 80 + (q4 << 4));
    const f32x4 zero = (f32x4){0.f, 0.f, 0.f, 0.f};
#pragma unroll
    for (int nt = 0; nt < 4; ++nt) {
      const int m = (w << 6) + (nt << 4) + il;
      const bf16x8 bfr = *(const bf16x8*)(h_mk + m * 80 + (q4 << 4));
      const f32x4 c = __builtin_amdgcn_mfma_f32_16x16x32_bf16(afr, bfr, zero, 0, 0, 0);
      if (q4 < 2) {
#pragma unroll
        for (int r = 0; r < 4; ++r)
          c16[(size_t)g * 2048 + (size_t)((q4 << 2) + r) * 256 + m] = f2bf(c[r]);
      }
    }
  }

  // ---- phase 4: op = sum_k a * v_nei   (W2c/b2 folded into proj)
  {
    const int n = tid;
    const int h = n >> 5;
    float o = 0.f;
    const size_t vbase = (size_t)(b << 12) * 256 + n;
#pragma unroll 4
    for (int k = 0; k < 32; ++k)
      o += at_lds[k][h] * bf2f(vb16[vbase + (size_t)nbr_s[k] * 256]);
    o_pre[(size_t)g * 256 + n] = o;
  }
}

// ---------------------------------------------------------------------------
// fused_small: round-5 structure (ws-constrained fallback). Writes complete
// attention output incl. W2c + b2 to o_pre; proj<false> applies Wp + bp.
// ---------------------------------------------------------------------------
__global__ __launch_bounds__(256) void fused_small(
    const float* __restrict__ xyz, const int* __restrict__ nbr_idx,
    const float* __restrict__ qbuf, const unsigned short* __restrict__ kb16,
    const unsigned short* __restrict__ vb16,
    const float* __restrict__ W1, const float* __restrict__ b1,
    const unsigned short* __restrict__ w2bf, const float* __restrict__ b2,
    float* __restrict__ o_pre) {
  __shared__ __align__(16) unsigned short h_lds[32 * 256];
  __shared__ float q_lds[256];
  __shared__ float u_lds[8][256];
  __shared__ float c_lds[8][256];
  __shared__ float at_lds[32][8];
  __shared__ float rel[32][3];
  __shared__ int nbr_s[32];

  const int g = blockIdx.x;
  const int b = g >> 12;
  const int p = g & (PB - 1);
  const int tid = threadIdx.x;

  if (tid < 32) {
    const int j = nbr_idx[(size_t)g * 32 + tid];
    nbr_s[tid] = j;
    const float* xb = xyz + (size_t)b * PB * 3;
    rel[tid][0] = xb[j * 3 + 0] - xb[p * 3 + 0];
    rel[tid][1] = xb[j * 3 + 1] - xb[p * 3 + 1];
    rel[tid][2] = xb[j * 3 + 2] - xb[p * 3 + 2];
  }
  q_lds[tid] = qbuf[(size_t)g * 256 + tid];
  __syncthreads();

  {
    const int half = tid >> 7;
    const int c0 = (tid & 127) << 1;
    const float w00 = W1[c0 * 3 + 0], w01 = W1[c0 * 3 + 1], w02 = W1[c0 * 3 + 2];
    const float w10 = W1[c0 * 3 + 3], w11 = W1[c0 * 3 + 4], w12 = W1[c0 * 3 + 5];
    const float bb0 = b1[c0], bb1 = b1[c0 + 1];
#pragma unroll 4
    for (int rl = 0; rl < 16; ++rl) {
      const int rr = (half << 4) + rl;
      const float rx = rel[rr][0], ry = rel[rr][1], rz = rel[rr][2];
      const float h0 = fmaxf(bb0 + rx * w00 + ry * w01 + rz * w02, 0.f);
      const float h1 = fmaxf(bb1 + rx * w10 + ry * w11 + rz * w12, 0.f);
      const unsigned pk = (unsigned)f2bf(h0) | ((unsigned)f2bf(h1) << 16);
      *(unsigned*)((char*)h_lds + (rr << 9) + (((unsigned)c0 << 1) ^ ((rr & 7) << 4))) = pk;
    }
  }
  {
    const int h = tid >> 5;
    const int m8 = (tid & 31) << 3;
    float ua[8];
#pragma unroll
    for (int j = 0; j < 8; ++j) ua[j] = 0.f;
    const unsigned short* wrow = w2bf + (size_t)(h << 5) * 256 + m8;
#pragma unroll 4
    for (int i = 0; i < 32; ++i) {
      const float qn = q_lds[(h << 5) + i];
      const bf16x8 wv = *(const bf16x8*)(wrow + (size_t)i * 256);
#pragma unroll
      for (int j = 0; j < 8; ++j) ua[j] += qn * bf2f((unsigned short)wv[j]);
    }
#pragma unroll
    for (int j = 0; j < 8; ++j) u_lds[h][m8 + j] = ua[j];
  }
  __syncthreads();

  {
    const int k = tid & 31;
    const int h = tid >> 5;
    const int j = nbr_s[k];
    const unsigned short* krow = kb16 + ((size_t)(b << 12) + j) * 256 + (h << 5);
    float s = 0.f;
#pragma unroll
    for (int c4 = 0; c4 < 4; ++c4) {
      const bf16x8 kv = *(const bf16x8*)(krow + (c4 << 3));
#pragma unroll
      for (int jj = 0; jj < 8; ++jj)
        s += q_lds[(h << 5) + (c4 << 3) + jj] * bf2f((unsigned short)kv[jj]);
    }
#pragma unroll 4
    for (int m8 = 0; m8 < 32; ++m8) {
      const bf16x8 hv = *(const bf16x8*)((const char*)h_lds + (k << 9) +
                                         ((m8 << 4) ^ ((k & 7) << 4)));
      const float4 u0 = *(const float4*)&u_lds[h][m8 << 3];
      const float4 u1 = *(const float4*)&u_lds[h][(m8 << 3) + 4];
      s += u0.x * bf2f((unsigned short)hv[0]) + u0.y * bf2f((unsigned short)hv[1]) +
           u0.z * bf2f((unsigned short)hv[2]) + u0.w * bf2f((unsigned short)hv[3]) +
           u1.x * bf2f((unsigned short)hv[4]) + u1.y * bf2f((unsigned short)hv[5]) +
           u1.z * bf2f((unsigned short)hv[6]) + u1.w * bf2f((unsigned short)hv[7]);
    }
    s *= SCALE_F;
    float mx = s;
#pragma unroll
    for (int off = 16; off; off >>= 1) mx = fmaxf(mx, __shfl_xor(mx, off));
    const float e = __expf(s - mx);
    float ssum = e;
#pragma unroll
    for (int off = 16; off; off >>= 1) ssum += __shfl_xor(ssum, off);
    at_lds[k][h] = e / ssum;
  }
  __syncthreads();

  {
    const int m = tid;
    float ca[8];
#pragma unroll
    for (int h = 0; h < 8; ++h) ca[h] = 0.f;
#pragma unroll 4
    for (int k = 0; k < 32; ++k) {
      const float hv = bf2f(*(const unsigned short*)(
          (const char*)h_lds + (k << 9) + ((2 * m) ^ ((k & 7) << 4))));
      const float4 a0 = *(const float4*)&at_lds[k][0];
      const float4 a1 = *(const float4*)&at_lds[k][4];
      ca[0] += a0.x * hv; ca[1] += a0.y * hv; ca[2] += a0.z * hv; ca[3] += a0.w * hv;
      ca[4] += a1.x * hv; ca[5] += a1.y * hv; ca[6] += a1.z * hv; ca[7] += a1.w * hv;
    }
#pragma unroll
    for (int h = 0; h < 8; ++h) c_lds[h][m] = ca[h];
  }
  __syncthreads();

  {
    const int n = tid;
    const int h = n >> 5;
    float o = b2[n];
    const size_t vbase = (size_t)(b << 12) * 256 + n;
#pragma unroll 4
    for (int k = 0; k < 32; ++k)
      o += at_lds[k][h] * bf2f(vb16[vbase + (size_t)nbr_s[k] * 256]);
    const unsigned short* wrow = w2bf + (size_t)n * 256;
    float opos = 0.f;
#pragma unroll 4
    for (int m8 = 0; m8 < 32; ++m8) {
      const bf16x8 wv = *(const bf16x8*)(wrow + (m8 << 3));
      const float4 c0 = *(const float4*)&c_lds[h][m8 << 3];
      const float4 c1 = *(const float4*)&c_lds[h][(m8 << 3) + 4];
      opos += c0.x * bf2f((unsigned short)wv[0]) + c0.y * bf2f((unsigned short)wv[1]) +
              c0.z * bf2f((unsigned short)wv[2]) + c0.w * bf2f((unsigned short)wv[3]) +
              c1.x * bf2f((unsigned short)wv[4]) + c1.y * bf2f((unsigned short)wv[5]) +
              c1.z * bf2f((unsigned short)wv[6]) + c1.w * bf2f((unsigned short)wv[7]);
    }
    o_pre[(size_t)g * 256 + n] = o + opos;
  }
}

// ---------------------------------------------------------------------------
extern "C" void kernel_launch(void* const* d_in, const int* in_sizes, int n_in,
                              void* d_out, int out_size, void* d_ws, size_t ws_size,
                              hipStream_t stream) {
  (void)in_sizes; (void)n_in; (void)out_size;
  const float* xyz   = (const float*)d_in[0];
  const float* feats = (const float*)d_in[1];
  const float* Wq    = (const float*)d_in[2];
  const float* Wk    = (const float*)d_in[3];
  const float* Wv    = (const float*)d_in[4];
  const float* Wp    = (const float*)d_in[5];
  const float* bp    = (const float*)d_in[6];
  const float* W1    = (const float*)d_in[7];
  const float* b1    = (const float*)d_in[8];
  const float* W2    = (const float*)d_in[9];
  const float* b2    = (const float*)d_in[10];
  float* out = (float*)d_out;

  // ws layout (float units) — sizes verified:
  //   idx 262144 | qb 2097152 | kb16 1048576 | vb16 1048576 | op 2097152
  //   whi 131072 | wlo 131072 | w2bf 32768 | wqut 262144 | wopt 262144
  //   bpp 256 | c16(=ubuf alias) 8388608   -> total 15761664 f = 63.05 MB
  float* wsf = (float*)d_ws;
  int* idxw            = (int*)wsf;
  float* qb            = wsf + 262144;
  unsigned short* kb16 = (unsigned short*)(wsf + 2359296);
  unsigned short* vb16 = (unsigned short*)(wsf + 3407872);
  float* op            = wsf + 4456448;
  unsigned short* whi  = (unsigned short*)(wsf + 6553600);
  unsigned short* wlo  = (unsigned short*)(wsf + 6684672);
  unsigned short* w2bf = (unsigned short*)(wsf + 6815744);
  unsigned short* wqut = (unsigned short*)(wsf + 6848512);
  unsigned short* wopt = (unsigned short*)(wsf + 7110656);
  float* bpp           = wsf + 7372800;
  unsigned short* c16  = (unsigned short*)(wsf + 7373056);  // also ubuf (aliased)
  const bool big = ws_size >= (size_t)15761664 * 4;

  hipLaunchKernelGGL(prep_w, dim3(1280), dim3(256), 0, stream,
                     Wq, Wk, Wv, Wp, W2, whi, wlo, w2bf);
  hipLaunchKernelGGL(knn_kernel, dim3(2 * PB), dim3(64), 0, stream, xyz, idxw);
  hipLaunchKernelGGL(qkv_mfma, dim3(768), dim3(256), 0, stream,
                     feats, whi, wlo, qb, kb16, vb16);
  if (big) {
    hipLaunchKernelGGL(wqu_kernel, dim3(2048), dim3(256), 0, stream, Wq, W2, wqut);
    hipLaunchKernelGGL(wop_kernel, dim3(2048), dim3(256), 0, stream, W2, Wp, wopt);
    hipLaunchKernelGGL(bpp_kernel, dim3(1), dim3(256), 0, stream, b2, Wp, bp, bpp);
    hipLaunchKernelGGL(u_mfma, dim3(256, 8), dim3(256), 0, stream,
                       feats, wqut, c16);
    hipLaunchKernelGGL(fused_big, dim3(2 * PB), dim3(256), 0, stream,
                       xyz, idxw, qb, kb16, vb16, W1, b1, c16, c16, op);
    hipLaunchKernelGGL(proj_mfma<true>, dim3(256), dim3(256), 0, stream,
                       op, whi + (size_t)3 * 65536, wlo + (size_t)3 * 65536,
                       c16, wopt, bpp, out);
  } else {
    hipLaunchKernelGGL(fused_small, dim3(2 * PB), dim3(256), 0, stream,
                       xyz, idxw, qb, kb16, vb16, W1, b1, w2bf, b2, op);
    hipLaunchKernelGGL(proj_mfma<false>, dim3(256), dim3(256), 0, stream,
                       op, whi + (size_t)3 * 65536, wlo + (size_t)3 * 65536,
                       nullptr, nullptr, bp, out);
  }
}

// Round 9
// 346.128 us; speedup vs baseline: 1.0342x; 1.0342x over previous
//
#include <hip/hip_runtime.h>
#include <cstddef>

#define PB 4096  // points per batch
static constexpr float SCALE_F = 0.17677669529663687f;  // 32^-0.5

typedef __attribute__((ext_vector_type(8))) short bf16x8;
typedef __attribute__((ext_vector_type(4))) float f32x4;

static __device__ __forceinline__ unsigned short f2bf(float x) {
  unsigned u = __builtin_bit_cast(unsigned, x);
  u += 0x7fffu + ((u >> 16) & 1u);  // RNE
  return (unsigned short)(u >> 16);
}
static __device__ __forceinline__ float bf2f(unsigned short h) {
  return __builtin_bit_cast(float, (unsigned)h << 16);
}

// ---------------------------------------------------------------------------
// kNN v2: 4 queries per 256-thread block (one wave each); xyz staged in LDS
// chunk-wise (shared by the 4 waves). Sorted top-32 distributed over lanes
// 0..31; ballot-driven O(1) insertion. fp32 distances with explicit rounding
// = exactly the reference's arithmetic.
// BUGFIX r8->r9: inserted index must be the CANDIDATE lane's point id
// ((c<<8)+(s<<6)+l), not the inserting lane's jl.
// ---------------------------------------------------------------------------
__global__ __launch_bounds__(256) void knn_kernel(const float* __restrict__ xyz,
                                                  int* __restrict__ idx_out) {
  __shared__ float xs[768];          // 256 points x 3
  const int wid = threadIdx.x >> 6;
  const int lane = threadIdx.x & 63;
  const int g = (blockIdx.x << 2) + wid;   // query id (4 per block, same batch)
  const int b = g >> 12;
  const int p = g & (PB - 1);
  const float* base = xyz + (size_t)b * PB * 3;
  const float qx = base[p * 3 + 0];
  const float qy = base[p * 3 + 1];
  const float qz = base[p * 3 + 2];
  float list_d = 3.4e38f;  // lanes 0..31 hold the sorted list
  int list_i = -1;
  for (int c = 0; c < 16; ++c) {     // 16 chunks of 256 points
    __syncthreads();
    const int src = c * 768 + threadIdx.x;
    xs[threadIdx.x]       = base[src];
    xs[threadIdx.x + 256] = base[src + 256];
    xs[threadIdx.x + 512] = base[src + 512];
    __syncthreads();
#pragma unroll
    for (int s = 0; s < 4; ++s) {
      const int jl = (s << 6) + lane;
      const float dx = __fsub_rn(qx, xs[jl * 3 + 0]);
      const float dy = __fsub_rn(qy, xs[jl * 3 + 1]);
      const float dz = __fsub_rn(qz, xs[jl * 3 + 2]);
      const float d2 = __fadd_rn(__fadd_rn(__fmul_rn(dx, dx), __fmul_rn(dy, dy)),
                                 __fmul_rn(dz, dz));
      float worst = __shfl(list_d, 31);
      unsigned long long mask = __ballot(d2 < worst);
      while (mask) {
        const int l = __ffsll(mask) - 1;
        mask &= mask - 1;
        const float v = __shfl(d2, l);
        worst = __shfl(list_d, 31);
        if (v < worst) {
          const unsigned long long gt = __ballot((lane < 32) && (list_d > v));
          const int pos = __ffsll(gt) - 1;
          const float pd = __shfl_up(list_d, 1);
          const int pi = __shfl_up(list_i, 1);
          if (lane < 32 && lane >= pos) {
            const bool at = (lane == pos);
            list_d = at ? v : pd;
            list_i = at ? ((c << 8) + (s << 6) + l) : pi;
          }
        }
      }
    }
  }
  if (lane < 32) idx_out[(size_t)g * 32 + lane] = list_i;
}

// ---------------------------------------------------------------------------
// Merged weight prep (one launch):
//   blk 0..1023    : bf16 hi/lo of Wq,Wk,Wv,Wp
//   blk 1024..1279 : w2bf
//   blk 1280..3327 : wqu_t[(h,m)][i] = sum_t Wq[h*32+t][i] * W2[h*32+t][m]
//   blk 3328..5375 : wop_t[j][(h,m)] = sum_t W2[h*32+t][m] * Wp[j][h*32+t]
//   blk 5376..5631 : bpp[j] = bp[j] + sum_n b2[n]*Wp[j][n] (coalesced reduce)
// ---------------------------------------------------------------------------
__global__ __launch_bounds__(256) void prep_all(
    const float* __restrict__ Wq, const float* __restrict__ Wk,
    const float* __restrict__ Wv, const float* __restrict__ Wp,
    const float* __restrict__ W2, const float* __restrict__ b2,
    const float* __restrict__ bp,
    unsigned short* __restrict__ whi, unsigned short* __restrict__ wlo,
    unsigned short* __restrict__ w2bf, unsigned short* __restrict__ wqu_t,
    unsigned short* __restrict__ wop_t, float* __restrict__ bpp) {
  __shared__ float sbuf[32];
  const int blk = blockIdx.x;
  const int tid = threadIdx.x;
  if (blk < 1024) {
    const int e = blk * 256 + tid;
    const int m = e >> 16;
    const int off = e & 65535;
    const float* src = (m == 0) ? Wq : (m == 1) ? Wk : (m == 2) ? Wv : Wp;
    const float x = src[off];
    const unsigned short hi = f2bf(x);
    whi[e] = hi;
    wlo[e] = f2bf(x - bf2f(hi));
  } else if (blk < 1280) {
    const int off = (blk - 1024) * 256 + tid;
    w2bf[off] = f2bf(W2[off]);
  } else if (blk < 3328) {
    const int hm = blk - 1280;
    const int h = hm >> 8;
    const int m = hm & 255;
    if (tid < 32) sbuf[tid] = W2[(size_t)((h << 5) + tid) * 256 + m];
    __syncthreads();
    float a = 0.f;
#pragma unroll 8
    for (int t = 0; t < 32; ++t)
      a += Wq[(size_t)((h << 5) + t) * 256 + tid] * sbuf[t];
    wqu_t[(size_t)hm * 256 + tid] = f2bf(a);
  } else if (blk < 5376) {
    const int e = blk - 3328;
    const int j = e & 255;
    const int h = e >> 8;
    if (tid < 32) sbuf[tid] = Wp[(size_t)j * 256 + (h << 5) + tid];
    __syncthreads();
    float a = 0.f;
#pragma unroll 8
    for (int t = 0; t < 32; ++t)
      a += W2[(size_t)((h << 5) + t) * 256 + tid] * sbuf[t];
    wop_t[(size_t)j * 2048 + (h << 8) + tid] = f2bf(a);
  } else {
    const int j = blk - 5376;
    float v = b2[tid] * Wp[(size_t)j * 256 + tid];
#pragma unroll
    for (int off = 32; off; off >>= 1) v += __shfl_xor(v, off);
    if ((tid & 63) == 0) sbuf[tid >> 6] = v;
    __syncthreads();
    if (tid == 0) bpp[j] = bp[j] + sbuf[0] + sbuf[1] + sbuf[2] + sbuf[3];
  }
}

// ---------------------------------------------------------------------------
// bf16x3 MFMA GEMM core: acc = A[r0..r0+31][:] @ W^T (W row-major hi/lo bf16).
// ---------------------------------------------------------------------------
static __device__ __forceinline__ void gemm32_core(
    const float* __restrict__ A, const unsigned short* __restrict__ wh,
    const unsigned short* __restrict__ wl, const int r0,
    unsigned short* ah, unsigned short* al, f32x4 acc[2][4]) {
  const int tid = threadIdx.x;
#pragma unroll
  for (int t = 0; t < 8; ++t) {
    const int idx4 = (t << 8) + tid;     // 2048 float4-slots = 32 rows x 64
    const int row = idx4 >> 6;
    const int c4 = idx4 & 63;
    const float4 v = *(const float4*)(A + (size_t)(r0 + row) * 256 + (c4 << 2));
    const unsigned short h0 = f2bf(v.x), h1 = f2bf(v.y);
    const unsigned short h2 = f2bf(v.z), h3 = f2bf(v.w);
    const unsigned short l0 = f2bf(v.x - bf2f(h0)), l1 = f2bf(v.y - bf2f(h1));
    const unsigned short l2 = f2bf(v.z - bf2f(h2)), l3 = f2bf(v.w - bf2f(h3));
    const int base = (row << 9) + ((c4 << 3) ^ ((row & 7) << 4));
    *(uint2*)((char*)ah + base) =
        make_uint2((unsigned)h0 | ((unsigned)h1 << 16),
                   (unsigned)h2 | ((unsigned)h3 << 16));
    *(uint2*)((char*)al + base) =
        make_uint2((unsigned)l0 | ((unsigned)l1 << 16),
                   (unsigned)l2 | ((unsigned)l3 << 16));
  }
  __syncthreads();
  const int lane = tid & 63;
  const int w = tid >> 6;
  const int il = lane & 15;
  const int q4 = lane >> 4;
#pragma unroll
  for (int mt = 0; mt < 2; ++mt)
#pragma unroll
    for (int nt = 0; nt < 4; ++nt) acc[mt][nt] = (f32x4){0.f, 0.f, 0.f, 0.f};
#pragma unroll 2
  for (int ks = 0; ks < 8; ++ks) {
    bf16x8 bh[4], bl[4], a0[2], a1[2];
#pragma unroll
    for (int nt = 0; nt < 4; ++nt) {
      const int n = (w << 6) + (nt << 4) + il;
      const size_t off = (size_t)n * 256 + (ks << 5) + (q4 << 3);
      bh[nt] = *(const bf16x8*)(wh + off);
      bl[nt] = *(const bf16x8*)(wl + off);
    }
#pragma unroll
    for (int mt = 0; mt < 2; ++mt) {
      const int row = (mt << 4) + il;
      const int byte = (row << 9) + ((((ks << 5) + (q4 << 3)) << 1) ^ ((row & 7) << 4));
      a0[mt] = *(const bf16x8*)((const char*)ah + byte);
      a1[mt] = *(const bf16x8*)((const char*)al + byte);
    }
#pragma unroll
    for (int mt = 0; mt < 2; ++mt)
#pragma unroll
      for (int nt = 0; nt < 4; ++nt) {
        acc[mt][nt] = __builtin_amdgcn_mfma_f32_16x16x32_bf16(a0[mt], bh[nt], acc[mt][nt], 0, 0, 0);
        acc[mt][nt] = __builtin_amdgcn_mfma_f32_16x16x32_bf16(a1[mt], bh[nt], acc[mt][nt], 0, 0, 0);
        acc[mt][nt] = __builtin_amdgcn_mfma_f32_16x16x32_bf16(a0[mt], bl[nt], acc[mt][nt], 0, 0, 0);
      }
  }
}

// ---------------------------------------------------------------------------
// Merged qkv + U GEMMs (one launch):
//   bid 0..767    : q/k/v rows (sel = bid%3, r-block = bid/3), hi/lo bf16x3
//   bid 768..2815 : U[8192][2048] = feats @ Wqu^T (single bf16)
// ---------------------------------------------------------------------------
__global__ __launch_bounds__(256) void qkvu_mfma(
    const float* __restrict__ feats,
    const unsigned short* __restrict__ whi, const unsigned short* __restrict__ wlo,
    const unsigned short* __restrict__ wqu_t,
    float* __restrict__ qb, unsigned short* __restrict__ kb16,
    unsigned short* __restrict__ vb16, unsigned short* __restrict__ U) {
  __shared__ __align__(16) unsigned short ah[32 * 256];
  __shared__ __align__(16) unsigned short al[32 * 256];
  const int bid = blockIdx.x;
  const int tid = threadIdx.x;
  const int lane = tid & 63;
  const int w = tid >> 6;
  const int il = lane & 15;
  const int q4 = lane >> 4;
  if (bid < 768) {
    const int sel = bid % 3;
    const int r0 = (bid / 3) << 5;
    const unsigned short* wh = whi + (size_t)sel * 65536;
    const unsigned short* wl = wlo + (size_t)sel * 65536;
    f32x4 acc[2][4];
    gemm32_core(feats, wh, wl, r0, ah, al, acc);
#pragma unroll
    for (int mt = 0; mt < 2; ++mt)
#pragma unroll
      for (int nt = 0; nt < 4; ++nt) {
        const int col = (w << 6) + (nt << 4) + il;
#pragma unroll
        for (int r = 0; r < 4; ++r) {
          const size_t e = (size_t)(r0 + (mt << 4) + (q4 << 2) + r) * 256 + col;
          if (sel == 0) qb[e] = acc[mt][nt][r];
          else if (sel == 1) kb16[e] = f2bf(acc[mt][nt][r]);
          else vb16[e] = f2bf(acc[mt][nt][r]);
        }
      }
  } else {
    const int t = bid - 768;
    const int r0 = (t & 255) << 5;
    const int cb = t >> 8;            // 0..7 column block
#pragma unroll
    for (int tt = 0; tt < 8; ++tt) {
      const int idx4 = (tt << 8) + tid;
      const int row = idx4 >> 6;
      const int c4 = idx4 & 63;
      const float4 v = *(const float4*)(feats + (size_t)(r0 + row) * 256 + (c4 << 2));
      const int base = (row << 9) + ((c4 << 3) ^ ((row & 7) << 4));
      *(uint2*)((char*)ah + base) =
          make_uint2((unsigned)f2bf(v.x) | ((unsigned)f2bf(v.y) << 16),
                     (unsigned)f2bf(v.z) | ((unsigned)f2bf(v.w) << 16));
    }
    __syncthreads();
    const unsigned short* wh = wqu_t + (size_t)cb * 65536;
    f32x4 acc[2][4];
#pragma unroll
    for (int mt = 0; mt < 2; ++mt)
#pragma unroll
      for (int nt = 0; nt < 4; ++nt) acc[mt][nt] = (f32x4){0.f, 0.f, 0.f, 0.f};
#pragma unroll 2
    for (int ks = 0; ks < 8; ++ks) {
      bf16x8 bh[4], a0[2];
#pragma unroll
      for (int nt = 0; nt < 4; ++nt) {
        const int n = (w << 6) + (nt << 4) + il;
        bh[nt] = *(const bf16x8*)(wh + (size_t)n * 256 + (ks << 5) + (q4 << 3));
      }
#pragma unroll
      for (int mt = 0; mt < 2; ++mt) {
        const int row = (mt << 4) + il;
        const int byte = (row << 9) + ((((ks << 5) + (q4 << 3)) << 1) ^ ((row & 7) << 4));
        a0[mt] = *(const bf16x8*)((const char*)ah + byte);
      }
#pragma unroll
      for (int mt = 0; mt < 2; ++mt)
#pragma unroll
        for (int nt = 0; nt < 4; ++nt)
          acc[mt][nt] = __builtin_amdgcn_mfma_f32_16x16x32_bf16(a0[mt], bh[nt], acc[mt][nt], 0, 0, 0);
    }
#pragma unroll
    for (int mt = 0; mt < 2; ++mt)
#pragma unroll
      for (int nt = 0; nt < 4; ++nt) {
        const int col = (w << 6) + (nt << 4) + il;
#pragma unroll
        for (int r = 0; r < 4; ++r)
          U[(size_t)(r0 + (mt << 4) + (q4 << 2) + r) * 2048 + (cb << 8) + col] =
              f2bf(acc[mt][nt][r]);
      }
  }
}

// proj: out = A @ Wp^T (+ c16 @ Wop^T if FOLD) + bias
template <bool FOLD>
__global__ __launch_bounds__(256) void proj_mfma(
    const float* __restrict__ A,
    const unsigned short* __restrict__ whi, const unsigned short* __restrict__ wlo,
    const unsigned short* __restrict__ c16, const unsigned short* __restrict__ wop_t,
    const float* __restrict__ bias, float* __restrict__ C) {
  __shared__ __align__(16) unsigned short ah[32 * 256];
  __shared__ __align__(16) unsigned short al[32 * 256];
  const int r0 = blockIdx.x << 5;
  f32x4 acc[2][4];
  gemm32_core(A, whi, wlo, r0, ah, al, acc);
  const int tid = threadIdx.x;
  const int lane = tid & 63;
  const int w = tid >> 6;
  const int il = lane & 15;
  const int q4 = lane >> 4;
  if (FOLD) {
#pragma unroll 4
    for (int ks2 = 0; ks2 < 64; ++ks2) {
      bf16x8 af[2];
#pragma unroll
      for (int mt = 0; mt < 2; ++mt)
        af[mt] = *(const bf16x8*)(c16 + (size_t)(r0 + (mt << 4) + il) * 2048 +
                                  (ks2 << 5) + (q4 << 3));
#pragma unroll
      for (int nt = 0; nt < 4; ++nt) {
        const int n = (w << 6) + (nt << 4) + il;
        const bf16x8 bf = *(const bf16x8*)(wop_t + (size_t)n * 2048 +
                                           (ks2 << 5) + (q4 << 3));
#pragma unroll
        for (int mt = 0; mt < 2; ++mt)
          acc[mt][nt] = __builtin_amdgcn_mfma_f32_16x16x32_bf16(af[mt], bf, acc[mt][nt], 0, 0, 0);
      }
    }
  }
#pragma unroll
  for (int mt = 0; mt < 2; ++mt)
#pragma unroll
    for (int nt = 0; nt < 4; ++nt) {
      const int col = (w << 6) + (nt << 4) + il;
      const float bv = bias[col];
#pragma unroll
      for (int r = 0; r < 4; ++r)
        C[(size_t)(r0 + (mt << 4) + (q4 << 2) + r) * 256 + col] = acc[mt][nt][r] + bv;
    }
}

// ---------------------------------------------------------------------------
// fused_big: algebraic form, MFMA'd inner products, u from precomputed ubuf.
// LDS = 52.5KB -> 3 blocks/CU. Attn weights live only in bf16 at16.
// ---------------------------------------------------------------------------
__global__ __launch_bounds__(256) void fused_big(
    const float* __restrict__ xyz, const int* __restrict__ nbr_idx,
    const float* __restrict__ qbuf, const unsigned short* __restrict__ kb16,
    const unsigned short* __restrict__ vb16,
    const float* __restrict__ W1, const float* __restrict__ b1,
    const unsigned short* __restrict__ ubuf,
    unsigned short* __restrict__ c16, float* __restrict__ o_pre) {
  __shared__ __align__(16) unsigned short h_km[32 * 256];  // 16KB swizzled
  __shared__ __align__(16) char h_mk[256 * 80];            // 20KB, pitch 80
  __shared__ __align__(16) unsigned short u16l[16 * 256];  // 8KB swizzled, rows 8+ zero
  __shared__ float sc_part[4][32][9];
  __shared__ __align__(16) char at16[16 * 80];             // pitch 80, rows 8+ zero
  __shared__ float q_lds[256];
  __shared__ float rel[32][3];
  __shared__ int nbr_s[32];

  const int g = blockIdx.x;
  const int b = g >> 12;
  const int p = g & (PB - 1);
  const int tid = threadIdx.x;

  // ---- phase 0: stage + zero-init
  if (tid < 32) {
    const int j = nbr_idx[(size_t)g * 32 + tid];
    nbr_s[tid] = j;
    const float* xb = xyz + (size_t)b * PB * 3;
    rel[tid][0] = xb[j * 3 + 0] - xb[p * 3 + 0];
    rel[tid][1] = xb[j * 3 + 1] - xb[p * 3 + 1];
    rel[tid][2] = xb[j * 3 + 2] - xb[p * 3 + 2];
  }
  q_lds[tid] = qbuf[(size_t)g * 256 + tid];
  *(uint4*)((char*)u16l + 4096 + tid * 16) = make_uint4(0, 0, 0, 0);
  if (tid < 160) *(unsigned*)(at16 + 640 + tid * 4) = 0;
  __syncthreads();

  // ---- phase 1: H = relu(relpos @ W1^T + b1), both layouts
  {
    const int half = tid >> 7;
    const int c0 = (tid & 127) << 1;
    const int stg = (tid >> 1) & 7;
    const float w00 = W1[c0 * 3 + 0], w01 = W1[c0 * 3 + 1], w02 = W1[c0 * 3 + 2];
    const float w10 = W1[c0 * 3 + 3], w11 = W1[c0 * 3 + 4], w12 = W1[c0 * 3 + 5];
    const float bb0 = b1[c0], bb1 = b1[c0 + 1];
#pragma unroll 4
    for (int rl = 0; rl < 16; ++rl) {
      const int rr = (half << 4) | ((rl + stg) & 15);
      const float rx = rel[rr][0], ry = rel[rr][1], rz = rel[rr][2];
      const float h0 = fmaxf(bb0 + rx * w00 + ry * w01 + rz * w02, 0.f);
      const float h1 = fmaxf(bb1 + rx * w10 + ry * w11 + rz * w12, 0.f);
      const unsigned short bh0 = f2bf(h0), bh1 = f2bf(h1);
      *(unsigned*)((char*)h_km + (rr << 9) + (((unsigned)c0 << 1) ^ ((rr & 7) << 4))) =
          (unsigned)bh0 | ((unsigned)bh1 << 16);
      *(unsigned short*)(h_mk + c0 * 80 + rr * 2) = bh0;
      *(unsigned short*)(h_mk + (c0 + 1) * 80 + rr * 2) = bh1;
    }
  }
  // ---- phase 1b: u16l rows 0..7 from ubuf (swizzled like h_km)
  {
    const int h = tid >> 5;
    const int byte = (h << 9) + ((((tid & 31) << 4)) ^ ((h & 7) << 4));
    const uint4 uv = *(const uint4*)(ubuf + (size_t)g * 2048 + tid * 8);
    *(uint4*)((char*)u16l + byte) = uv;
  }
  __syncthreads();

  const int lane = tid & 63;
  const int w = tid >> 6;
  const int il = lane & 15;
  const int q4 = lane >> 4;
  const int kk = tid & 31;
  const int hh = tid >> 5;

  // ---- phase 2: s_qk (scalar) + S_pos (MFMA partials over m-chunks)
  float sqk = 0.f;
  {
    const int j = nbr_s[kk];
    const unsigned short* krow = kb16 + ((size_t)(b << 12) + j) * 256 + (hh << 5);
#pragma unroll
    for (int c4 = 0; c4 < 4; ++c4) {
      const bf16x8 kv = *(const bf16x8*)(krow + (c4 << 3));
#pragma unroll
      for (int jj = 0; jj < 8; ++jj)
        sqk += q_lds[(hh << 5) + (c4 << 3) + jj] * bf2f((unsigned short)kv[jj]);
    }
  }
  {
    f32x4 accp[2];
    accp[0] = (f32x4){0.f, 0.f, 0.f, 0.f};
    accp[1] = (f32x4){0.f, 0.f, 0.f, 0.f};
#pragma unroll
    for (int ksl = 0; ksl < 2; ++ksl) {
      const int m0 = (w << 6) + (ksl << 5) + (q4 << 3);  // element index
      const bf16x8 bfr = *(const bf16x8*)((char*)u16l + (il << 9) +
                                          (((unsigned)m0 << 1) ^ ((il & 7) << 4)));
#pragma unroll
      for (int mt = 0; mt < 2; ++mt) {
        const int row = (mt << 4) + il;
        const bf16x8 afr = *(const bf16x8*)((char*)h_km + (row << 9) +
                                            (((unsigned)m0 << 1) ^ ((row & 7) << 4)));
        accp[mt] = __builtin_amdgcn_mfma_f32_16x16x32_bf16(afr, bfr, accp[mt], 0, 0, 0);
      }
    }
    if (il < 8) {
#pragma unroll
      for (int mt = 0; mt < 2; ++mt)
#pragma unroll
        for (int r = 0; r < 4; ++r)
          sc_part[w][(mt << 4) + (q4 << 2) + r][il] = accp[mt][r];
    }
  }
  __syncthreads();

  // ---- phase 2b: combine + softmax; attn -> at16 (bf16)
  {
    float s = sqk + sc_part[0][kk][hh] + sc_part[1][kk][hh] +
              sc_part[2][kk][hh] + sc_part[3][kk][hh];
    s *= SCALE_F;
    float mx = s;
#pragma unroll
    for (int off = 16; off; off >>= 1) mx = fmaxf(mx, __shfl_xor(mx, off));
    const float e = __expf(s - mx);
    float ssum = e;
#pragma unroll
    for (int off = 16; off; off >>= 1) ssum += __shfl_xor(ssum, off);
    *(unsigned short*)(at16 + hh * 80 + kk * 2) = f2bf(e / ssum);
  }
  __syncthreads();

  // ---- phase 3: C8 = attn16 @ H -> c16 global (overwrites ubuf row g)
  {
    const bf16x8 afr = *(const bf16x8*)(at16 + il * 80 + (q4 << 4));
    const f32x4 zero = (f32x4){0.f, 0.f, 0.f, 0.f};
#pragma unroll
    for (int nt = 0; nt < 4; ++nt) {
      const int m = (w << 6) + (nt << 4) + il;
      const bf16x8 bfr = *(const bf16x8*)(h_mk + m * 80 + (q4 << 4));
      const f32x4 c = __builtin_amdgcn_mfma_f32_16x16x32_bf16(afr, bfr, zero, 0, 0, 0);
      if (q4 < 2) {
#pragma unroll
        for (int r = 0; r < 4; ++r)
          c16[(size_t)g * 2048 + (size_t)((q4 << 2) + r) * 256 + m] = f2bf(c[r]);
      }
    }
  }

  // ---- phase 4: op = sum_k a * v_nei   (W2c/b2 folded into proj)
  {
    const int n = tid;
    const int h = n >> 5;
    float o = 0.f;
    const size_t vbase = (size_t)(b << 12) * 256 + n;
#pragma unroll 4
    for (int k = 0; k < 32; ++k) {
      const float aw = bf2f(*(const unsigned short*)(at16 + h * 80 + k * 2));
      o += aw * bf2f(vb16[vbase + (size_t)nbr_s[k] * 256]);
    }
    o_pre[(size_t)g * 256 + n] = o;
  }
}

// ---------------------------------------------------------------------------
// fused_small: ws-constrained fallback (round-5 structure, complete output).
// ---------------------------------------------------------------------------
__global__ __launch_bounds__(256) void fused_small(
    const float* __restrict__ xyz, const int* __restrict__ nbr_idx,
    const float* __restrict__ qbuf, const unsigned short* __restrict__ kb16,
    const unsigned short* __restrict__ vb16,
    const float* __restrict__ W1, const float* __restrict__ b1,
    const unsigned short* __restrict__ w2bf, const float* __restrict__ b2,
    float* __restrict__ o_pre) {
  __shared__ __align__(16) unsigned short h_lds[32 * 256];
  __shared__ float q_lds[256];
  __shared__ float u_lds[8][256];
  __shared__ float c_lds[8][256];
  __shared__ float at_lds[32][8];
  __shared__ float rel[32][3];
  __shared__ int nbr_s[32];

  const int g = blockIdx.x;
  const int b = g >> 12;
  const int p = g & (PB - 1);
  const int tid = threadIdx.x;

  if (tid < 32) {
    const int j = nbr_idx[(size_t)g * 32 + tid];
    nbr_s[tid] = j;
    const float* xb = xyz + (size_t)b * PB * 3;
    rel[tid][0] = xb[j * 3 + 0] - xb[p * 3 + 0];
    rel[tid][1] = xb[j * 3 + 1] - xb[p * 3 + 1];
    rel[tid][2] = xb[j * 3 + 2] - xb[p * 3 + 2];
  }
  q_lds[tid] = qbuf[(size_t)g * 256 + tid];
  __syncthreads();

  {
    const int half = tid >> 7;
    const int c0 = (tid & 127) << 1;
    const float w00 = W1[c0 * 3 + 0], w01 = W1[c0 * 3 + 1], w02 = W1[c0 * 3 + 2];
    const float w10 = W1[c0 * 3 + 3], w11 = W1[c0 * 3 + 4], w12 = W1[c0 * 3 + 5];
    const float bb0 = b1[c0], bb1 = b1[c0 + 1];
#pragma unroll 4
    for (int rl = 0; rl < 16; ++rl) {
      const int rr = (half << 4) + rl;
      const float rx = rel[rr][0], ry = rel[rr][1], rz = rel[rr][2];
      const float h0 = fmaxf(bb0 + rx * w00 + ry * w01 + rz * w02, 0.f);
      const float h1 = fmaxf(bb1 + rx * w10 + ry * w11 + rz * w12, 0.f);
      const unsigned pk = (unsigned)f2bf(h0) | ((unsigned)f2bf(h1) << 16);
      *(unsigned*)((char*)h_lds + (rr << 9) + (((unsigned)c0 << 1) ^ ((rr & 7) << 4))) = pk;
    }
  }
  {
    const int h = tid >> 5;
    const int m8 = (tid & 31) << 3;
    float ua[8];
#pragma unroll
    for (int j = 0; j < 8; ++j) ua[j] = 0.f;
    const unsigned short* wrow = w2bf + (size_t)(h << 5) * 256 + m8;
#pragma unroll 4
    for (int i = 0; i < 32; ++i) {
      const float qn = q_lds[(h << 5) + i];
      const bf16x8 wv = *(const bf16x8*)(wrow + (size_t)i * 256);
#pragma unroll
      for (int j = 0; j < 8; ++j) ua[j] += qn * bf2f((unsigned short)wv[j]);
    }
#pragma unroll
    for (int j = 0; j < 8; ++j) u_lds[h][m8 + j] = ua[j];
  }
  __syncthreads();

  {
    const int k = tid & 31;
    const int h = tid >> 5;
    const int j = nbr_s[k];
    const unsigned short* krow = kb16 + ((size_t)(b << 12) + j) * 256 + (h << 5);
    float s = 0.f;
#pragma unroll
    for (int c4 = 0; c4 < 4; ++c4) {
      const bf16x8 kv = *(const bf16x8*)(krow + (c4 << 3));
#pragma unroll
      for (int jj = 0; jj < 8; ++jj)
        s += q_lds[(h << 5) + (c4 << 3) + jj] * bf2f((unsigned short)kv[jj]);
    }
#pragma unroll 4
    for (int m8 = 0; m8 < 32; ++m8) {
      const bf16x8 hv = *(const bf16x8*)((const char*)h_lds + (k << 9) +
                                         ((m8 << 4) ^ ((k & 7) << 4)));
      const float4 u0 = *(const float4*)&u_lds[h][m8 << 3];
      const float4 u1 = *(const float4*)&u_lds[h][(m8 << 3) + 4];
      s += u0.x * bf2f((unsigned short)hv[0]) + u0.y * bf2f((unsigned short)hv[1]) +
           u0.z * bf2f((unsigned short)hv[2]) + u0.w * bf2f((unsigned short)hv[3]) +
           u1.x * bf2f((unsigned short)hv[4]) + u1.y * bf2f((unsigned short)hv[5]) +
           u1.z * bf2f((unsigned short)hv[6]) + u1.w * bf2f((unsigned short)hv[7]);
    }
    s *= SCALE_F;
    float mx = s;
#pragma unroll
    for (int off = 16; off; off >>= 1) mx = fmaxf(mx, __shfl_xor(mx, off));
    const float e = __expf(s - mx);
    float ssum = e;
#pragma unroll
    for (int off = 16; off; off >>= 1) ssum += __shfl_xor(ssum, off);
    at_lds[k][h] = e / ssum;
  }
  __syncthreads();

  {
    const int m = tid;
    float ca[8];
#pragma unroll
    for (int h = 0; h < 8; ++h) ca[h] = 0.f;
#pragma unroll 4
    for (int k = 0; k < 32; ++k) {
      const float hv = bf2f(*(const unsigned short*)(
          (const char*)h_lds + (k << 9) + ((2 * m) ^ ((k & 7) << 4))));
      const float4 a0 = *(const float4*)&at_lds[k][0];
      const float4 a1 = *(const float4*)&at_lds[k][4];
      ca[0] += a0.x * hv; ca[1] += a0.y * hv; ca[2] += a0.z * hv; ca[3] += a0.w * hv;
      ca[4] += a1.x * hv; ca[5] += a1.y * hv; ca[6] += a1.z * hv; ca[7] += a1.w * hv;
    }
#pragma unroll
    for (int h = 0; h < 8; ++h) c_lds[h][m] = ca[h];
  }
  __syncthreads();

  {
    const int n = tid;
    const int h = n >> 5;
    float o = b2[n];
    const size_t vbase = (size_t)(b << 12) * 256 + n;
#pragma unroll 4
    for (int k = 0; k < 32; ++k)
      o += at_lds[k][h] * bf2f(vb16[vbase + (size_t)nbr_s[k] * 256]);
    const unsigned short* wrow = w2bf + (size_t)n * 256;
    float opos = 0.f;
#pragma unroll 4
    for (int m8 = 0; m8 < 32; ++m8) {
      const bf16x8 wv = *(const bf16x8*)(wrow + (m8 << 3));
      const float4 c0 = *(const float4*)&c_lds[h][m8 << 3];
      const float4 c1 = *(const float4*)&c_lds[h][(m8 << 3) + 4];
      opos += c0.x * bf2f((unsigned short)wv[0]) + c0.y * bf2f((unsigned short)wv[1]) +
              c0.z * bf2f((unsigned short)wv[2]) + c0.w * bf2f((unsigned short)wv[3]) +
              c1.x * bf2f((unsigned short)wv[4]) + c1.y * bf2f((unsigned short)wv[5]) +
              c1.z * bf2f((unsigned short)wv[6]) + c1.w * bf2f((unsigned short)wv[7]);
    }
    o_pre[(size_t)g * 256 + n] = o + opos;
  }
}

// ---------------------------------------------------------------------------
extern "C" void kernel_launch(void* const* d_in, const int* in_sizes, int n_in,
                              void* d_out, int out_size, void* d_ws, size_t ws_size,
                              hipStream_t stream) {
  (void)in_sizes; (void)n_in; (void)out_size;
  const float* xyz   = (const float*)d_in[0];
  const float* feats = (const float*)d_in[1];
  const float* Wq    = (const float*)d_in[2];
  const float* Wk    = (const float*)d_in[3];
  const float* Wv    = (const float*)d_in[4];
  const float* Wp    = (const float*)d_in[5];
  const float* bp    = (const float*)d_in[6];
  const float* W1    = (const float*)d_in[7];
  const float* b1    = (const float*)d_in[8];
  const float* W2    = (const float*)d_in[9];
  const float* b2    = (const float*)d_in[10];
  float* out = (float*)d_out;

  // ws layout (float units): idx 262144 | qb 2097152 | kb16 1048576 |
  // vb16 1048576 | op 2097152 | whi 131072 | wlo 131072 | w2bf 32768 |
  // wqut 262144 | wopt 262144 | bpp 256 | c16(=ubuf alias) 8388608
  // total 15761664 f = 63.05 MB
  float* wsf = (float*)d_ws;
  int* idxw            = (int*)wsf;
  float* qb            = wsf + 262144;
  unsigned short* kb16 = (unsigned short*)(wsf + 2359296);
  unsigned short* vb16 = (unsigned short*)(wsf + 3407872);
  float* op            = wsf + 4456448;
  unsigned short* whi  = (unsigned short*)(wsf + 6553600);
  unsigned short* wlo  = (unsigned short*)(wsf + 6684672);
  unsigned short* w2bf = (unsigned short*)(wsf + 6815744);
  unsigned short* wqut = (unsigned short*)(wsf + 6848512);
  unsigned short* wopt = (unsigned short*)(wsf + 7110656);
  float* bpp           = wsf + 7372800;
  unsigned short* c16  = (unsigned short*)(wsf + 7373056);  // also ubuf (aliased)
  const bool big = ws_size >= (size_t)15761664 * 4;

  hipLaunchKernelGGL(prep_all, dim3(big ? 5632 : 1280), dim3(256), 0, stream,
                     Wq, Wk, Wv, Wp, W2, b2, bp, whi, wlo, w2bf, wqut, wopt, bpp);
  hipLaunchKernelGGL(knn_kernel, dim3(2 * PB / 4), dim3(256), 0, stream, xyz, idxw);
  hipLaunchKernelGGL(qkvu_mfma, dim3(big ? 2816 : 768), dim3(256), 0, stream,
                     feats, whi, wlo, wqut, qb, kb16, vb16, c16);
  if (big) {
    hipLaunchKernelGGL(fused_big, dim3(2 * PB), dim3(256), 0, stream,
                       xyz, idxw, qb, kb16, vb16, W1, b1, c16, c16, op);
    hipLaunchKernelGGL(proj_mfma<true>, dim3(256), dim3(256), 0, stream,
                       op, whi + (size_t)3 * 65536, wlo + (size_t)3 * 65536,
                       c16, wopt, bpp, out);
  } else {
    hipLaunchKernelGGL(fused_small, dim3(2 * PB), dim3(256), 0, stream,
                       xyz, idxw, qb, kb16, vb16, W1, b1, w2bf, b2, op);
    hipLaunchKernelGGL(proj_mfma<false>, dim3(256), dim3(256), 0, stream,
                       op, whi + (size_t)3 * 65536, wlo + (size_t)3 * 65536,
                       nullptr, nullptr, bp, out);
  }
}

// Round 10
// 340.794 us; speedup vs baseline: 1.0504x; 1.0157x over previous
//
#include <hip/hip_runtime.h>
#include <cstddef>

#define PB 4096  // points per batch
static constexpr float SCALE_F = 0.17677669529663687f;  // 32^-0.5

typedef __attribute__((ext_vector_type(8))) short bf16x8;
typedef __attribute__((ext_vector_type(4))) float f32x4;

static __device__ __forceinline__ unsigned short f2bf(float x) {
  unsigned u = __builtin_bit_cast(unsigned, x);
  u += 0x7fffu + ((u >> 16) & 1u);  // RNE
  return (unsigned short)(u >> 16);
}
static __device__ __forceinline__ float bf2f(unsigned short h) {
  return __builtin_bit_cast(float, (unsigned)h << 16);
}

// ---------------------------------------------------------------------------
// kNN: 4 queries per 256-thread block; xyz staged in LDS chunk-wise.
// Sorted top-32 distributed over lanes 0..31; ballot-driven O(1) insertion.
// ---------------------------------------------------------------------------
__global__ __launch_bounds__(256) void knn_kernel(const float* __restrict__ xyz,
                                                  int* __restrict__ idx_out) {
  __shared__ float xs[768];          // 256 points x 3
  const int wid = threadIdx.x >> 6;
  const int lane = threadIdx.x & 63;
  const int g = (blockIdx.x << 2) + wid;   // query id (4 per block, same batch)
  const int b = g >> 12;
  const int p = g & (PB - 1);
  const float* base = xyz + (size_t)b * PB * 3;
  const float qx = base[p * 3 + 0];
  const float qy = base[p * 3 + 1];
  const float qz = base[p * 3 + 2];
  float list_d = 3.4e38f;  // lanes 0..31 hold the sorted list
  int list_i = -1;
  for (int c = 0; c < 16; ++c) {     // 16 chunks of 256 points
    __syncthreads();
    const int src = c * 768 + threadIdx.x;
    xs[threadIdx.x]       = base[src];
    xs[threadIdx.x + 256] = base[src + 256];
    xs[threadIdx.x + 512] = base[src + 512];
    __syncthreads();
#pragma unroll
    for (int s = 0; s < 4; ++s) {
      const int jl = (s << 6) + lane;
      const float dx = __fsub_rn(qx, xs[jl * 3 + 0]);
      const float dy = __fsub_rn(qy, xs[jl * 3 + 1]);
      const float dz = __fsub_rn(qz, xs[jl * 3 + 2]);
      const float d2 = __fadd_rn(__fadd_rn(__fmul_rn(dx, dx), __fmul_rn(dy, dy)),
                                 __fmul_rn(dz, dz));
      float worst = __shfl(list_d, 31);
      unsigned long long mask = __ballot(d2 < worst);
      while (mask) {
        const int l = __ffsll(mask) - 1;
        mask &= mask - 1;
        const float v = __shfl(d2, l);
        worst = __shfl(list_d, 31);
        if (v < worst) {
          const unsigned long long gt = __ballot((lane < 32) && (list_d > v));
          const int pos = __ffsll(gt) - 1;
          const float pd = __shfl_up(list_d, 1);
          const int pi = __shfl_up(list_i, 1);
          if (lane < 32 && lane >= pos) {
            const bool at = (lane == pos);
            list_d = at ? v : pd;
            list_i = at ? ((c << 8) + (s << 6) + l) : pi;
          }
        }
      }
    }
  }
  if (lane < 32) idx_out[(size_t)g * 32 + lane] = list_i;
}

// ---------------------------------------------------------------------------
// Merged weight prep (one launch). Same block ranges as round 9.
// ---------------------------------------------------------------------------
__global__ __launch_bounds__(256) void prep_all(
    const float* __restrict__ Wq, const float* __restrict__ Wk,
    const float* __restrict__ Wv, const float* __restrict__ Wp,
    const float* __restrict__ W2, const float* __restrict__ b2,
    const float* __restrict__ bp,
    unsigned short* __restrict__ whi, unsigned short* __restrict__ wlo,
    unsigned short* __restrict__ w2bf, unsigned short* __restrict__ wqu_t,
    unsigned short* __restrict__ wop_t, float* __restrict__ bpp) {
  __shared__ float sbuf[32];
  const int blk = blockIdx.x;
  const int tid = threadIdx.x;
  if (blk < 1024) {
    const int e = blk * 256 + tid;
    const int m = e >> 16;
    const int off = e & 65535;
    const float* src = (m == 0) ? Wq : (m == 1) ? Wk : (m == 2) ? Wv : Wp;
    const float x = src[off];
    const unsigned short hi = f2bf(x);
    whi[e] = hi;
    wlo[e] = f2bf(x - bf2f(hi));
  } else if (blk < 1280) {
    const int off = (blk - 1024) * 256 + tid;
    w2bf[off] = f2bf(W2[off]);
  } else if (blk < 3328) {
    const int hm = blk - 1280;
    const int h = hm >> 8;
    const int m = hm & 255;
    if (tid < 32) sbuf[tid] = W2[(size_t)((h << 5) + tid) * 256 + m];
    __syncthreads();
    float a = 0.f;
#pragma unroll 8
    for (int t = 0; t < 32; ++t)
      a += Wq[(size_t)((h << 5) + t) * 256 + tid] * sbuf[t];
    wqu_t[(size_t)hm * 256 + tid] = f2bf(a);
  } else if (blk < 5376) {
    const int e = blk - 3328;
    const int j = e & 255;
    const int h = e >> 8;
    if (tid < 32) sbuf[tid] = Wp[(size_t)j * 256 + (h << 5) + tid];
    __syncthreads();
    float a = 0.f;
#pragma unroll 8
    for (int t = 0; t < 32; ++t)
      a += W2[(size_t)((h << 5) + t) * 256 + tid] * sbuf[t];
    wop_t[(size_t)j * 2048 + (h << 8) + tid] = f2bf(a);
  } else {
    const int j = blk - 5376;
    float v = b2[tid] * Wp[(size_t)j * 256 + tid];
#pragma unroll
    for (int off = 32; off; off >>= 1) v += __shfl_xor(v, off);
    if ((tid & 63) == 0) sbuf[tid >> 6] = v;
    __syncthreads();
    if (tid == 0) bpp[j] = bp[j] + sbuf[0] + sbuf[1] + sbuf[2] + sbuf[3];
  }
}

// ---------------------------------------------------------------------------
// bf16x3 MFMA GEMM core: acc = A[r0..r0+31][:] @ W^T (W row-major hi/lo bf16).
// ---------------------------------------------------------------------------
static __device__ __forceinline__ void gemm32_core(
    const float* __restrict__ A, const unsigned short* __restrict__ wh,
    const unsigned short* __restrict__ wl, const int r0,
    unsigned short* ah, unsigned short* al, f32x4 acc[2][4]) {
  const int tid = threadIdx.x;
#pragma unroll
  for (int t = 0; t < 8; ++t) {
    const int idx4 = (t << 8) + tid;     // 2048 float4-slots = 32 rows x 64
    const int row = idx4 >> 6;
    const int c4 = idx4 & 63;
    const float4 v = *(const float4*)(A + (size_t)(r0 + row) * 256 + (c4 << 2));
    const unsigned short h0 = f2bf(v.x), h1 = f2bf(v.y);
    const unsigned short h2 = f2bf(v.z), h3 = f2bf(v.w);
    const unsigned short l0 = f2bf(v.x - bf2f(h0)), l1 = f2bf(v.y - bf2f(h1));
    const unsigned short l2 = f2bf(v.z - bf2f(h2)), l3 = f2bf(v.w - bf2f(h3));
    const int base = (row << 9) + ((c4 << 3) ^ ((row & 7) << 4));
    *(uint2*)((char*)ah + base) =
        make_uint2((unsigned)h0 | ((unsigned)h1 << 16),
                   (unsigned)h2 | ((unsigned)h3 << 16));
    *(uint2*)((char*)al + base) =
        make_uint2((unsigned)l0 | ((unsigned)l1 << 16),
                   (unsigned)l2 | ((unsigned)l3 << 16));
  }
  __syncthreads();
  const int lane = tid & 63;
  const int w = tid >> 6;
  const int il = lane & 15;
  const int q4 = lane >> 4;
#pragma unroll
  for (int mt = 0; mt < 2; ++mt)
#pragma unroll
    for (int nt = 0; nt < 4; ++nt) acc[mt][nt] = (f32x4){0.f, 0.f, 0.f, 0.f};
#pragma unroll 2
  for (int ks = 0; ks < 8; ++ks) {
    bf16x8 bh[4], bl[4], a0[2], a1[2];
#pragma unroll
    for (int nt = 0; nt < 4; ++nt) {
      const int n = (w << 6) + (nt << 4) + il;
      const size_t off = (size_t)n * 256 + (ks << 5) + (q4 << 3);
      bh[nt] = *(const bf16x8*)(wh + off);
      bl[nt] = *(const bf16x8*)(wl + off);
    }
#pragma unroll
    for (int mt = 0; mt < 2; ++mt) {
      const int row = (mt << 4) + il;
      const int byte = (row << 9) + ((((ks << 5) + (q4 << 3)) << 1) ^ ((row & 7) << 4));
      a0[mt] = *(const bf16x8*)((const char*)ah + byte);
      a1[mt] = *(const bf16x8*)((const char*)al + byte);
    }
#pragma unroll
    for (int mt = 0; mt < 2; ++mt)
#pragma unroll
      for (int nt = 0; nt < 4; ++nt) {
        acc[mt][nt] = __builtin_amdgcn_mfma_f32_16x16x32_bf16(a0[mt], bh[nt], acc[mt][nt], 0, 0, 0);
        acc[mt][nt] = __builtin_amdgcn_mfma_f32_16x16x32_bf16(a1[mt], bh[nt], acc[mt][nt], 0, 0, 0);
        acc[mt][nt] = __builtin_amdgcn_mfma_f32_16x16x32_bf16(a0[mt], bl[nt], acc[mt][nt], 0, 0, 0);
      }
  }
}

// ---------------------------------------------------------------------------
// qkvu: bid 0..767 = q/k/v (M=32, hi/lo bf16x3, LDS-bounced coalesced writes);
//       bid 768..1791 = U (M=64 tiles, single bf16, 2x arithmetic intensity).
// ---------------------------------------------------------------------------
__global__ __launch_bounds__(256) void qkvu_mfma(
    const float* __restrict__ feats,
    const unsigned short* __restrict__ whi, const unsigned short* __restrict__ wlo,
    const unsigned short* __restrict__ wqu_t,
    float* __restrict__ qb, unsigned short* __restrict__ kb16,
    unsigned short* __restrict__ vb16, unsigned short* __restrict__ U) {
  __shared__ __align__(16) unsigned short smem[64 * 256];  // 32KB
  unsigned short* ah = smem;
  unsigned short* al = smem + 32 * 256;
  const int bid = blockIdx.x;
  const int tid = threadIdx.x;
  const int lane = tid & 63;
  const int w = tid >> 6;
  const int il = lane & 15;
  const int q4 = lane >> 4;
  if (bid < 768) {
    const int sel = bid % 3;
    const int r0 = (bid / 3) << 5;
    f32x4 acc[2][4];
    gemm32_core(feats, whi + (size_t)sel * 65536, wlo + (size_t)sel * 65536,
                r0, ah, al, acc);
    __syncthreads();  // protect smem (staging) before reuse as output bounce
    if (sel == 0) {   // fp32 q: bounce in smem as float[32][256]
      float* fb = (float*)smem;
#pragma unroll
      for (int mt = 0; mt < 2; ++mt)
#pragma unroll
        for (int nt = 0; nt < 4; ++nt)
#pragma unroll
          for (int r = 0; r < 4; ++r)
            fb[((mt << 4) + (q4 << 2) + r) * 256 + (w << 6) + (nt << 4) + il] =
                acc[mt][nt][r];
      __syncthreads();
      float* dst = qb + (size_t)r0 * 256;
#pragma unroll
      for (int i = 0; i < 8; ++i)
        *(float4*)(dst + tid * 32 + (i << 2)) = *(float4*)(fb + tid * 32 + (i << 2));
    } else {          // bf16 k/v: bounce as ushort[32][256]
#pragma unroll
      for (int mt = 0; mt < 2; ++mt)
#pragma unroll
        for (int nt = 0; nt < 4; ++nt)
#pragma unroll
          for (int r = 0; r < 4; ++r)
            smem[((mt << 4) + (q4 << 2) + r) * 256 + (w << 6) + (nt << 4) + il] =
                f2bf(acc[mt][nt][r]);
      __syncthreads();
      unsigned short* dst = ((sel == 1) ? kb16 : vb16) + (size_t)r0 * 256;
#pragma unroll
      for (int i = 0; i < 4; ++i)
        *(uint4*)(dst + tid * 32 + (i << 3)) = *(uint4*)(smem + tid * 32 + (i << 3));
    }
  } else {
    // ---- U path: M=64, K=256, N=256 cols (cb selects which 256 of 2048)
    const int t = bid - 768;
    const int r0 = (t & 127) << 6;    // 128 row-blocks of 64
    const int cb = t >> 7;            // 0..7 column block
#pragma unroll
    for (int tt = 0; tt < 16; ++tt) {
      const int idx4 = (tt << 8) + tid;     // 4096 float4-slots = 64 rows x 64
      const int row = idx4 >> 6;
      const int c4 = idx4 & 63;
      const float4 v = *(const float4*)(feats + (size_t)(r0 + row) * 256 + (c4 << 2));
      const int base = (row << 9) + ((c4 << 3) ^ ((row & 7) << 4));
      *(uint2*)((char*)smem + base) =
          make_uint2((unsigned)f2bf(v.x) | ((unsigned)f2bf(v.y) << 16),
                     (unsigned)f2bf(v.z) | ((unsigned)f2bf(v.w) << 16));
    }
    __syncthreads();
    const unsigned short* wh = wqu_t + (size_t)cb * 65536;
    f32x4 acc[4][4];
#pragma unroll
    for (int mt = 0; mt < 4; ++mt)
#pragma unroll
      for (int nt = 0; nt < 4; ++nt) acc[mt][nt] = (f32x4){0.f, 0.f, 0.f, 0.f};
#pragma unroll 2
    for (int ks = 0; ks < 8; ++ks) {
      bf16x8 bh[4], a0[4];
#pragma unroll
      for (int nt = 0; nt < 4; ++nt) {
        const int n = (w << 6) + (nt << 4) + il;
        bh[nt] = *(const bf16x8*)(wh + (size_t)n * 256 + (ks << 5) + (q4 << 3));
      }
#pragma unroll
      for (int mt = 0; mt < 4; ++mt) {
        const int row = (mt << 4) + il;
        const int byte = (row << 9) + ((((ks << 5) + (q4 << 3)) << 1) ^ ((row & 7) << 4));
        a0[mt] = *(const bf16x8*)((const char*)smem + byte);
      }
#pragma unroll
      for (int mt = 0; mt < 4; ++mt)
#pragma unroll
        for (int nt = 0; nt < 4; ++nt)
          acc[mt][nt] = __builtin_amdgcn_mfma_f32_16x16x32_bf16(a0[mt], bh[nt], acc[mt][nt], 0, 0, 0);
    }
    __syncthreads();  // staging reads done; reuse smem as output bounce
#pragma unroll
    for (int mt = 0; mt < 4; ++mt)
#pragma unroll
      for (int nt = 0; nt < 4; ++nt)
#pragma unroll
        for (int r = 0; r < 4; ++r)
          smem[((mt << 4) + (q4 << 2) + r) * 256 + (w << 6) + (nt << 4) + il] =
              f2bf(acc[mt][nt][r]);
    __syncthreads();
    // coalesced write: 4 threads per row, 64 bf16 each (512B/row segments)
    {
      const int row = tid >> 2;
      const int c0 = (tid & 3) << 6;
      unsigned short* dst = U + (size_t)(r0 + row) * 2048 + (cb << 8) + c0;
      const unsigned short* srcl = smem + row * 256 + c0;
#pragma unroll
      for (int i = 0; i < 8; ++i)
        *(uint4*)(dst + (i << 3)) = *(const uint4*)(srcl + (i << 3));
    }
  }
}

// ---------------------------------------------------------------------------
// proj: out = A @ Wp^T (+ c16 @ Wop^T if FOLD) + bias.
// FOLD reads c16 through chunked LDS staging (coalesced 256B row segments).
// ---------------------------------------------------------------------------
template <bool FOLD>
__global__ __launch_bounds__(256) void proj_mfma(
    const float* __restrict__ A,
    const unsigned short* __restrict__ whi, const unsigned short* __restrict__ wlo,
    const unsigned short* __restrict__ c16, const unsigned short* __restrict__ wop_t,
    const float* __restrict__ bias, float* __restrict__ C) {
  __shared__ __align__(16) unsigned short smem[64 * 256];  // 32KB
  unsigned short* ah = smem;
  unsigned short* al = smem + 32 * 256;
  const int r0 = blockIdx.x << 5;
  f32x4 acc[2][4];
  gemm32_core(A, whi, wlo, r0, ah, al, acc);
  const int tid = threadIdx.x;
  const int lane = tid & 63;
  const int w = tid >> 6;
  const int il = lane & 15;
  const int q4 = lane >> 4;
  if (FOLD) {
    // 16 chunks of [32 rows x 128 K]; each staged coalesced then 4 sub-K MFMAs
    for (int ch = 0; ch < 16; ++ch) {
      __syncthreads();  // protect previous chunk's reads (and core staging)
#pragma unroll
      for (int pass = 0; pass < 2; ++pass) {
        const int idx = (pass << 8) + tid;      // 512 slots = 32 rows x 16
        const int row = idx >> 4;
        const int c16i = idx & 15;              // 16B units within row
        const uint4 v = *(const uint4*)(c16 + (size_t)(r0 + row) * 2048 +
                                        (ch << 7) + (c16i << 3));
        *(uint4*)((char*)smem + row * 256 + ((c16i << 4) ^ ((row & 7) << 4))) = v;
      }
      __syncthreads();
#pragma unroll
      for (int sub = 0; sub < 4; ++sub) {
        bf16x8 af[2];
#pragma unroll
        for (int mt = 0; mt < 2; ++mt) {
          const int row = (mt << 4) + il;
          af[mt] = *(const bf16x8*)((const char*)smem + row * 256 +
                                    (((sub << 6) + (q4 << 4)) ^ ((row & 7) << 4)));
        }
#pragma unroll
        for (int nt = 0; nt < 4; ++nt) {
          const int n = (w << 6) + (nt << 4) + il;
          const bf16x8 bf = *(const bf16x8*)(wop_t + (size_t)n * 2048 +
                                             (ch << 7) + (sub << 5) + (q4 << 3));
#pragma unroll
          for (int mt = 0; mt < 2; ++mt)
            acc[mt][nt] = __builtin_amdgcn_mfma_f32_16x16x32_bf16(af[mt], bf, acc[mt][nt], 0, 0, 0);
        }
      }
    }
  }
#pragma unroll
  for (int mt = 0; mt < 2; ++mt)
#pragma unroll
    for (int nt = 0; nt < 4; ++nt) {
      const int col = (w << 6) + (nt << 4) + il;
      const float bv = bias[col];
#pragma unroll
      for (int r = 0; r < 4; ++r)
        C[(size_t)(r0 + (mt << 4) + (q4 << 2) + r) * 256 + col] = acc[mt][nt][r] + bv;
    }
}

// ---------------------------------------------------------------------------
// fused_big: algebraic form. Phase-3 c16 writes now LDS-bounced (coalesced
// 16B/lane linear stores) via a buffer unioned with the dead sc_part.
// ---------------------------------------------------------------------------
__global__ __launch_bounds__(256) void fused_big(
    const float* __restrict__ xyz, const int* __restrict__ nbr_idx,
    const float* __restrict__ qbuf, const unsigned short* __restrict__ kb16,
    const unsigned short* __restrict__ vb16,
    const float* __restrict__ W1, const float* __restrict__ b1,
    const unsigned short* __restrict__ ubuf,
    unsigned short* __restrict__ c16, float* __restrict__ o_pre) {
  __shared__ __align__(16) unsigned short h_km[32 * 256];  // 16KB swizzled
  __shared__ __align__(16) char h_mk[256 * 80];            // 20KB, pitch 80
  __shared__ __align__(16) unsigned short u16l[16 * 256];  // 8KB swizzled, rows 8+ zero
  __shared__ __align__(16) char scpad[4608];               // sc_part THEN c8 bounce
  __shared__ __align__(16) char at16[16 * 80];             // pitch 80, rows 8+ zero
  __shared__ float q_lds[256];
  __shared__ float rel[32][3];
  __shared__ int nbr_s[32];
  float (*sc_part)[32][9] = (float (*)[32][9])scpad;

  const int g = blockIdx.x;
  const int b = g >> 12;
  const int p = g & (PB - 1);
  const int tid = threadIdx.x;

  // ---- phase 0: stage + zero-init
  if (tid < 32) {
    const int j = nbr_idx[(size_t)g * 32 + tid];
    nbr_s[tid] = j;
    const float* xb = xyz + (size_t)b * PB * 3;
    rel[tid][0] = xb[j * 3 + 0] - xb[p * 3 + 0];
    rel[tid][1] = xb[j * 3 + 1] - xb[p * 3 + 1];
    rel[tid][2] = xb[j * 3 + 2] - xb[p * 3 + 2];
  }
  q_lds[tid] = qbuf[(size_t)g * 256 + tid];
  *(uint4*)((char*)u16l + 4096 + tid * 16) = make_uint4(0, 0, 0, 0);
  if (tid < 160) *(unsigned*)(at16 + 640 + tid * 4) = 0;
  __syncthreads();

  // ---- phase 1: H = relu(relpos @ W1^T + b1), both layouts
  {
    const int half = tid >> 7;
    const int c0 = (tid & 127) << 1;
    const int stg = (tid >> 1) & 7;
    const float w00 = W1[c0 * 3 + 0], w01 = W1[c0 * 3 + 1], w02 = W1[c0 * 3 + 2];
    const float w10 = W1[c0 * 3 + 3], w11 = W1[c0 * 3 + 4], w12 = W1[c0 * 3 + 5];
    const float bb0 = b1[c0], bb1 = b1[c0 + 1];
#pragma unroll 4
    for (int rl = 0; rl < 16; ++rl) {
      const int rr = (half << 4) | ((rl + stg) & 15);
      const float rx = rel[rr][0], ry = rel[rr][1], rz = rel[rr][2];
      const float h0 = fmaxf(bb0 + rx * w00 + ry * w01 + rz * w02, 0.f);
      const float h1 = fmaxf(bb1 + rx * w10 + ry * w11 + rz * w12, 0.f);
      const unsigned short bh0 = f2bf(h0), bh1 = f2bf(h1);
      *(unsigned*)((char*)h_km + (rr << 9) + (((unsigned)c0 << 1) ^ ((rr & 7) << 4))) =
          (unsigned)bh0 | ((unsigned)bh1 << 16);
      *(unsigned short*)(h_mk + c0 * 80 + rr * 2) = bh0;
      *(unsigned short*)(h_mk + (c0 + 1) * 80 + rr * 2) = bh1;
    }
  }
  // ---- phase 1b: u16l rows 0..7 from ubuf (swizzled like h_km)
  {
    const int h = tid >> 5;
    const int byte = (h << 9) + ((((tid & 31) << 4)) ^ ((h & 7) << 4));
    const uint4 uv = *(const uint4*)(ubuf + (size_t)g * 2048 + tid * 8);
    *(uint4*)((char*)u16l + byte) = uv;
  }
  __syncthreads();

  const int lane = tid & 63;
  const int w = tid >> 6;
  const int il = lane & 15;
  const int q4 = lane >> 4;
  const int kk = tid & 31;
  const int hh = tid >> 5;

  // ---- phase 2: s_qk (scalar) + S_pos (MFMA partials over m-chunks)
  float sqk = 0.f;
  {
    const int j = nbr_s[kk];
    const unsigned short* krow = kb16 + ((size_t)(b << 12) + j) * 256 + (hh << 5);
#pragma unroll
    for (int c4 = 0; c4 < 4; ++c4) {
      const bf16x8 kv = *(const bf16x8*)(krow + (c4 << 3));
#pragma unroll
      for (int jj = 0; jj < 8; ++jj)
        sqk += q_lds[(hh << 5) + (c4 << 3) + jj] * bf2f((unsigned short)kv[jj]);
    }
  }
  {
    f32x4 accp[2];
    accp[0] = (f32x4){0.f, 0.f, 0.f, 0.f};
    accp[1] = (f32x4){0.f, 0.f, 0.f, 0.f};
#pragma unroll
    for (int ksl = 0; ksl < 2; ++ksl) {
      const int m0 = (w << 6) + (ksl << 5) + (q4 << 3);  // element index
      const bf16x8 bfr = *(const bf16x8*)((char*)u16l + (il << 9) +
                                          (((unsigned)m0 << 1) ^ ((il & 7) << 4)));
#pragma unroll
      for (int mt = 0; mt < 2; ++mt) {
        const int row = (mt << 4) + il;
        const bf16x8 afr = *(const bf16x8*)((char*)h_km + (row << 9) +
                                            (((unsigned)m0 << 1) ^ ((row & 7) << 4)));
        accp[mt] = __builtin_amdgcn_mfma_f32_16x16x32_bf16(afr, bfr, accp[mt], 0, 0, 0);
      }
    }
    if (il < 8) {
#pragma unroll
      for (int mt = 0; mt < 2; ++mt)
#pragma unroll
        for (int r = 0; r < 4; ++r)
          sc_part[w][(mt << 4) + (q4 << 2) + r][il] = accp[mt][r];
    }
  }
  __syncthreads();

  // ---- phase 2b: combine + softmax; attn -> at16 (bf16)
  {
    float s = sqk + sc_part[0][kk][hh] + sc_part[1][kk][hh] +
              sc_part[2][kk][hh] + sc_part[3][kk][hh];
    s *= SCALE_F;
    float mx = s;
#pragma unroll
    for (int off = 16; off; off >>= 1) mx = fmaxf(mx, __shfl_xor(mx, off));
    const float e = __expf(s - mx);
    float ssum = e;
#pragma unroll
    for (int off = 16; off; off >>= 1) ssum += __shfl_xor(ssum, off);
    *(unsigned short*)(at16 + hh * 80 + kk * 2) = f2bf(e / ssum);
  }
  __syncthreads();   // at16 ready; sc_part dead -> scpad reusable as c8 bounce

  // ---- phase 3: C8 = attn16 @ H -> bounce to LDS -> coalesced c16 write
  {
    unsigned short* c8b = (unsigned short*)scpad;
    const bf16x8 afr = *(const bf16x8*)(at16 + il * 80 + (q4 << 4));
    const f32x4 zero = (f32x4){0.f, 0.f, 0.f, 0.f};
#pragma unroll
    for (int nt = 0; nt < 4; ++nt) {
      const int m = (w << 6) + (nt << 4) + il;
      const bf16x8 bfr = *(const bf16x8*)(h_mk + m * 80 + (q4 << 4));
      const f32x4 c = __builtin_amdgcn_mfma_f32_16x16x32_bf16(afr, bfr, zero, 0, 0, 0);
      if (q4 < 2) {
#pragma unroll
        for (int r = 0; r < 4; ++r)
          c8b[((q4 << 2) + r) * 256 + m] = f2bf(c[r]);
      }
    }
    __syncthreads();
    *(uint4*)(c16 + (size_t)g * 2048 + tid * 8) = *(const uint4*)(c8b + tid * 8);
  }

  // ---- phase 4: op = sum_k a * v_nei   (W2c/b2 folded into proj)
  {
    const int n = tid;
    const int h = n >> 5;
    float o = 0.f;
    const size_t vbase = (size_t)(b << 12) * 256 + n;
#pragma unroll 4
    for (int k = 0; k < 32; ++k) {
      const float aw = bf2f(*(const unsigned short*)(at16 + h * 80 + k * 2));
      o += aw * bf2f(vb16[vbase + (size_t)nbr_s[k] * 256]);
    }
    o_pre[(size_t)g * 256 + n] = o;
  }
}

// ---------------------------------------------------------------------------
// fused_small: ws-constrained fallback (round-5 structure, complete output).
// ---------------------------------------------------------------------------
__global__ __launch_bounds__(256) void fused_small(
    const float* __restrict__ xyz, const int* __restrict__ nbr_idx,
    const float* __restrict__ qbuf, const unsigned short* __restrict__ kb16,
    const unsigned short* __restrict__ vb16,
    const float* __restrict__ W1, const float* __restrict__ b1,
    const unsigned short* __restrict__ w2bf, const float* __restrict__ b2,
    float* __restrict__ o_pre) {
  __shared__ __align__(16) unsigned short h_lds[32 * 256];
  __shared__ float q_lds[256];
  __shared__ float u_lds[8][256];
  __shared__ float c_lds[8][256];
  __shared__ float at_lds[32][8];
  __shared__ float rel[32][3];
  __shared__ int nbr_s[32];

  const int g = blockIdx.x;
  const int b = g >> 12;
  const int p = g & (PB - 1);
  const int tid = threadIdx.x;

  if (tid < 32) {
    const int j = nbr_idx[(size_t)g * 32 + tid];
    nbr_s[tid] = j;
    const float* xb = xyz + (size_t)b * PB * 3;
    rel[tid][0] = xb[j * 3 + 0] - xb[p * 3 + 0];
    rel[tid][1] = xb[j * 3 + 1] - xb[p * 3 + 1];
    rel[tid][2] = xb[j * 3 + 2] - xb[p * 3 + 2];
  }
  q_lds[tid] = qbuf[(size_t)g * 256 + tid];
  __syncthreads();

  {
    const int half = tid >> 7;
    const int c0 = (tid & 127) << 1;
    const float w00 = W1[c0 * 3 + 0], w01 = W1[c0 * 3 + 1], w02 = W1[c0 * 3 + 2];
    const float w10 = W1[c0 * 3 + 3], w11 = W1[c0 * 3 + 4], w12 = W1[c0 * 3 + 5];
    const float bb0 = b1[c0], bb1 = b1[c0 + 1];
#pragma unroll 4
    for (int rl = 0; rl < 16; ++rl) {
      const int rr = (half << 4) + rl;
      const float rx = rel[rr][0], ry = rel[rr][1], rz = rel[rr][2];
      const float h0 = fmaxf(bb0 + rx * w00 + ry * w01 + rz * w02, 0.f);
      const float h1 = fmaxf(bb1 + rx * w10 + ry * w11 + rz * w12, 0.f);
      const unsigned pk = (unsigned)f2bf(h0) | ((unsigned)f2bf(h1) << 16);
      *(unsigned*)((char*)h_lds + (rr << 9) + (((unsigned)c0 << 1) ^ ((rr & 7) << 4))) = pk;
    }
  }
  {
    const int h = tid >> 5;
    const int m8 = (tid & 31) << 3;
    float ua[8];
#pragma unroll
    for (int j = 0; j < 8; ++j) ua[j] = 0.f;
    const unsigned short* wrow = w2bf + (size_t)(h << 5) * 256 + m8;
#pragma unroll 4
    for (int i = 0; i < 32; ++i) {
      const float qn = q_lds[(h << 5) + i];
      const bf16x8 wv = *(const bf16x8*)(wrow + (size_t)i * 256);
#pragma unroll
      for (int j = 0; j < 8; ++j) ua[j] += qn * bf2f((unsigned short)wv[j]);
    }
#pragma unroll
    for (int j = 0; j < 8; ++j) u_lds[h][m8 + j] = ua[j];
  }
  __syncthreads();

  {
    const int k = tid & 31;
    const int h = tid >> 5;
    const int j = nbr_s[k];
    const unsigned short* krow = kb16 + ((size_t)(b << 12) + j) * 256 + (h << 5);
    float s = 0.f;
#pragma unroll
    for (int c4 = 0; c4 < 4; ++c4) {
      const bf16x8 kv = *(const bf16x8*)(krow + (c4 << 3));
#pragma unroll
      for (int jj = 0; jj < 8; ++jj)
        s += q_lds[(h << 5) + (c4 << 3) + jj] * bf2f((unsigned short)kv[jj]);
    }
#pragma unroll 4
    for (int m8 = 0; m8 < 32; ++m8) {
      const bf16x8 hv = *(const bf16x8*)((const char*)h_lds + (k << 9) +
                                         ((m8 << 4) ^ ((k & 7) << 4)));
      const float4 u0 = *(const float4*)&u_lds[h][m8 << 3];
      const float4 u1 = *(const float4*)&u_lds[h][(m8 << 3) + 4];
      s += u0.x * bf2f((unsigned short)hv[0]) + u0.y * bf2f((unsigned short)hv[1]) +
           u0.z * bf2f((unsigned short)hv[2]) + u0.w * bf2f((unsigned short)hv[3]) +
           u1.x * bf2f((unsigned short)hv[4]) + u1.y * bf2f((unsigned short)hv[5]) +
           u1.z * bf2f((unsigned short)hv[6]) + u1.w * bf2f((unsigned short)hv[7]);
    }
    s *= SCALE_F;
    float mx = s;
#pragma unroll
    for (int off = 16; off; off >>= 1) mx = fmaxf(mx, __shfl_xor(mx, off));
    const float e = __expf(s - mx);
    float ssum = e;
#pragma unroll
    for (int off = 16; off; off >>= 1) ssum += __shfl_xor(ssum, off);
    at_lds[k][h] = e / ssum;
  }
  __syncthreads();

  {
    const int m = tid;
    float ca[8];
#pragma unroll
    for (int h = 0; h < 8; ++h) ca[h] = 0.f;
#pragma unroll 4
    for (int k = 0; k < 32; ++k) {
      const float hv = bf2f(*(const unsigned short*)(
          (const char*)h_lds + (k << 9) + ((2 * m) ^ ((k & 7) << 4))));
      const float4 a0 = *(const float4*)&at_lds[k][0];
      const float4 a1 = *(const float4*)&at_lds[k][4];
      ca[0] += a0.x * hv; ca[1] += a0.y * hv; ca[2] += a0.z * hv; ca[3] += a0.w * hv;
      ca[4] += a1.x * hv; ca[5] += a1.y * hv; ca[6] += a1.z * hv; ca[7] += a1.w * hv;
    }
#pragma unroll
    for (int h = 0; h < 8; ++h) c_lds[h][m] = ca[h];
  }
  __syncthreads();

  {
    const int n = tid;
    const int h = n >> 5;
    float o = b2[n];
    const size_t vbase = (size_t)(b << 12) * 256 + n;
#pragma unroll 4
    for (int k = 0; k < 32; ++k)
      o += at_lds[k][h] * bf2f(vb16[vbase + (size_t)nbr_s[k] * 256]);
    const unsigned short* wrow = w2bf + (size_t)n * 256;
    float opos = 0.f;
#pragma unroll 4
    for (int m8 = 0; m8 < 32; ++m8) {
      const bf16x8 wv = *(const bf16x8*)(wrow + (m8 << 3));
      const float4 c0 = *(const float4*)&c_lds[h][m8 << 3];
      const float4 c1 = *(const float4*)&c_lds[h][(m8 << 3) + 4];
      opos += c0.x * bf2f((unsigned short)wv[0]) + c0.y * bf2f((unsigned short)wv[1]) +
              c0.z * bf2f((unsigned short)wv[2]) + c0.w * bf2f((unsigned short)wv[3]) +
              c1.x * bf2f((unsigned short)wv[4]) + c1.y * bf2f((unsigned short)wv[5]) +
              c1.z * bf2f((unsigned short)wv[6]) + c1.w * bf2f((unsigned short)wv[7]);
    }
    o_pre[(size_t)g * 256 + n] = o + opos;
  }
}

// ---------------------------------------------------------------------------
extern "C" void kernel_launch(void* const* d_in, const int* in_sizes, int n_in,
                              void* d_out, int out_size, void* d_ws, size_t ws_size,
                              hipStream_t stream) {
  (void)in_sizes; (void)n_in; (void)out_size;
  const float* xyz   = (const float*)d_in[0];
  const float* feats = (const float*)d_in[1];
  const float* Wq    = (const float*)d_in[2];
  const float* Wk    = (const float*)d_in[3];
  const float* Wv    = (const float*)d_in[4];
  const float* Wp    = (const float*)d_in[5];
  const float* bp    = (const float*)d_in[6];
  const float* W1    = (const float*)d_in[7];
  const float* b1    = (const float*)d_in[8];
  const float* W2    = (const float*)d_in[9];
  const float* b2    = (const float*)d_in[10];
  float* out = (float*)d_out;

  // ws layout (float units): idx 262144 | qb 2097152 | kb16 1048576 |
  // vb16 1048576 | op 2097152 | whi 131072 | wlo 131072 | w2bf 32768 |
  // wqut 262144 | wopt 262144 | bpp 256 | c16(=ubuf alias) 8388608
  // total 15761664 f = 63.05 MB
  float* wsf = (float*)d_ws;
  int* idxw            = (int*)wsf;
  float* qb            = wsf + 262144;
  unsigned short* kb16 = (unsigned short*)(wsf + 2359296);
  unsigned short* vb16 = (unsigned short*)(wsf + 3407872);
  float* op            = wsf + 4456448;
  unsigned short* whi  = (unsigned short*)(wsf + 6553600);
  unsigned short* wlo  = (unsigned short*)(wsf + 6684672);
  unsigned short* w2bf = (unsigned short*)(wsf + 6815744);
  unsigned short* wqut = (unsigned short*)(wsf + 6848512);
  unsigned short* wopt = (unsigned short*)(wsf + 7110656);
  float* bpp           = wsf + 7372800;
  unsigned short* c16  = (unsigned short*)(wsf + 7373056);  // also ubuf (aliased)
  const bool big = ws_size >= (size_t)15761664 * 4;

  hipLaunchKernelGGL(prep_all, dim3(big ? 5632 : 1280), dim3(256), 0, stream,
                     Wq, Wk, Wv, Wp, W2, b2, bp, whi, wlo, w2bf, wqut, wopt, bpp);
  hipLaunchKernelGGL(knn_kernel, dim3(2 * PB / 4), dim3(256), 0, stream, xyz, idxw);
  hipLaunchKernelGGL(qkvu_mfma, dim3(big ? 1792 : 768), dim3(256), 0, stream,
                     feats, whi, wlo, wqut, qb, kb16, vb16, c16);
  if (big) {
    hipLaunchKernelGGL(fused_big, dim3(2 * PB), dim3(256), 0, stream,
                       xyz, idxw, qb, kb16, vb16, W1, b1, c16, c16, op);
    hipLaunchKernelGGL(proj_mfma<true>, dim3(256), dim3(256), 0, stream,
                       op, whi + (size_t)3 * 65536, wlo + (size_t)3 * 65536,
                       c16, wopt, bpp, out);
  } else {
    hipLaunchKernelGGL(fused_small, dim3(2 * PB), dim3(256), 0, stream,
                       xyz, idxw, qb, kb16, vb16, W1, b1, w2bf, b2, op);
    hipLaunchKernelGGL(proj_mfma<false>, dim3(256), dim3(256), 0, stream,
                       op, whi + (size_t)3 * 65536, wlo + (size_t)3 * 65536,
                       nullptr, nullptr, bp, out);
  }
}